// Round 8
// baseline (648.004 us; speedup 1.0000x reference)
//
#include <hip/hip_runtime.h>
#include <hip/hip_bf16.h>

typedef __hip_bfloat16 bf16;

typedef __bf16 bfv8 __attribute__((ext_vector_type(8)));
typedef float f32x4 __attribute__((ext_vector_type(4)));

__device__ __forceinline__ float lrelu(float x) { return x > 0.f ? x : 0.01f * x; }

__device__ __forceinline__ float ldv(float v) { return v; }
__device__ __forceinline__ float ldv(bf16 v) { return __bfloat162float(v); }
__device__ __forceinline__ void stv(float* p, float v) { *p = v; }
__device__ __forceinline__ void stv(bf16* p, float v) { *p = __float2bfloat16(v); }

__device__ __forceinline__ float in_rd(const void* p, size_t i, int isbf) {
  return isbf ? __bfloat162float(((const bf16*)p)[i]) : ((const float*)p)[i];
}
__device__ __forceinline__ int ix_rd(const void* p, size_t i, int is64) {
  return is64 ? (int)((const long long*)p)[i] : ((const int*)p)[i];
}

// ---------------- fused per-array format probe: one launch, 23 blocks ----------------
struct ProbeArgs {
  const void* p[23];
  int s[23];
  int mode[23];
};

__global__ void detect_all(ProbeArgs a, int* __restrict__ flags) {
  __shared__ int sh[256];
  int b = blockIdx.x;
  const unsigned int* w = (const unsigned int*)a.p[b];
  int s = a.s[b], mode = a.mode[b];
  int t = threadIdx.x;
  int c = 0;
  if (t < s) {
    if (mode == 0) {
      unsigned int v = w[t];
      int e = (v >> 7) & 0xFF;
      c = (e >= 100 && e <= 140) ? 1 : 0;
    } else {
      c = (w[2 * t + 1] == 0u) ? 1 : 0;
    }
  }
  sh[t] = c;
  __syncthreads();
  for (int d = 128; d; d >>= 1) {
    if (t < d) sh[t] += sh[t + d];
    __syncthreads();
  }
  if (t == 0) flags[b] = (mode == 0) ? (sh[0] * 10 >= 7 * s) : (sh[0] * 10 >= 9 * s);
}

// ---------------- weight prep ----------------
// fp32 region (floats): [0,16384) W_inT [k,n]; [16384,32768) W_o1T [k,n]; [32768,49152) root;
// [49152,81920) rw; [81920] b_in; [82048] rgcn_bias; [82176] b_o1; [82304] W_o2; [82560] b_o2
// bf16 region (float index BF_BASE): 5x [128][128] bf16 [out][in]:
//   m=0 WinB; m=1 Wo1B; m=2 rootB; m=3 rwB0; m=4 rwB1
// ENC region (float index ENC_BASE): EncU bf16[128][128]; EncT bf16[128][128]; biasU; biasT
#define PW_F32 82562
#define BF_BASE 82564
#define PW_W_TOTAL (BF_BASE + 5 * 8192)
#define ENC_BASE PW_W_TOTAL
#define PW_TOTAL (ENC_BASE + 16384 + 256)
__global__ void prep_weights(const void* Win, const void* bin, const void* rw,
                             const void* root, const void* rb, const void* Wo1,
                             const void* bo1, const void* Wo2, const void* bo2,
                             const int* __restrict__ fl, float* __restrict__ pw) {
  int i = blockIdx.x * 256 + threadIdx.x;
  if (i >= PW_W_TOTAL) return;
  if (i < 16384) {
    int k = i >> 7, o = i & 127;
    pw[i] = in_rd(Win, (size_t)o * 128 + k, fl[14]);
  } else if (i < 32768) {
    int j = i - 16384;
    int k = j >> 7, o = j & 127;
    pw[i] = in_rd(Wo1, (size_t)o * 128 + k, fl[19]);
  } else if (i < 49152) {
    pw[i] = in_rd(root, i - 32768, fl[17]);
  } else if (i < 81920) {
    pw[i] = in_rd(rw, i - 49152, fl[16]);
  } else if (i < 82048) {
    pw[i] = in_rd(bin, i - 81920, fl[15]);
  } else if (i < 82176) {
    pw[i] = in_rd(rb, i - 82048, fl[18]);
  } else if (i < 82304) {
    pw[i] = in_rd(bo1, i - 82176, fl[20]);
  } else if (i < 82560) {
    pw[i] = in_rd(Wo2, i - 82304, fl[21]);
  } else if (i < PW_F32) {
    pw[i] = in_rd(bo2, i - 82560, fl[22]);
  } else if (i >= BF_BASE) {
    int j = i - BF_BASE;
    bf16* bw = (bf16*)(pw + BF_BASE);
#pragma unroll
    for (int q = 0; q < 2; q++) {
      int u = 2 * j + q;
      int m = u >> 14, r = u & 16383;
      int n = r >> 7, k = r & 127;
      float v;
      if (m == 0) v = in_rd(Win, (size_t)n * 128 + k, fl[14]);
      else if (m == 1) v = in_rd(Wo1, (size_t)n * 128 + k, fl[19]);
      else if (m == 2) v = in_rd(root, (size_t)k * 128 + n, fl[17]);
      else v = in_rd(rw, (size_t)(m - 3) * 16384 + (size_t)k * 128 + n, fl[16]);
      bw[u] = __float2bfloat16(v);
    }
  }
}

// Builds fused encoder weights/biases.
__global__ void prep_enc(const void* Wd, const void* bd, const void* Wn, const void* bn,
                         const void* Wc, const void* bc, const void* Wt, const void* bt,
                         const int* __restrict__ fl, int dDes, int dNum, int dCat, int dTw,
                         float* __restrict__ pw) {
  int i = blockIdx.x * 256 + threadIdx.x;
  bf16* e = (bf16*)(pw + ENC_BASE);
  float* bU = pw + ENC_BASE + 16384;
  float* bT = bU + 128;
  if (i < 16384) {
    int n = i >> 7, k = i & 127;
    float v = 0.f;
    if (n < 64) {
      if (k < dDes) v = in_rd(Wd, (size_t)n * dDes + k, fl[6]);
    } else if (n < 96) {
      int kk = k - dDes;
      if (kk >= 0 && kk < dNum) v = in_rd(Wn, (size_t)(n - 64) * dNum + kk, fl[8]);
    } else {
      int kk = k - dDes - dNum;
      if (kk >= 0 && kk < dCat) v = in_rd(Wc, (size_t)(n - 96) * dCat + kk, fl[10]);
    }
    e[i] = __float2bfloat16(v);
  } else if (i < 32768) {
    int j = i - 16384;
    int n = j >> 7, k = j & 127;
    float v = (k < dTw) ? in_rd(Wt, (size_t)n * dTw + k, fl[12]) : 0.f;
    e[i] = __float2bfloat16(v);
  } else if (i < 32896) {
    int j = i - 32768;
    bU[j] = (j < 64) ? in_rd(bd, j, fl[7])
                     : (j < 96) ? in_rd(bn, j - 64, fl[9]) : in_rd(bc, j - 96, fl[11]);
  } else if (i < 33024) {
    bT[i - 32896] = in_rd(bt, i - 32896, fl[13]);
  }
}

// ---------------- utilities ----------------
__global__ void sig_fill(float* __restrict__ p, int n, float v) {
  int i = blockIdx.x * 256 + threadIdx.x;
  if (i < n) p[i] = v;
}
__global__ void zero_ints(int* __restrict__ p, int n) {
  int i = blockIdx.x * 256 + threadIdx.x;
  if (i < n) p[i] = 0;
}

// ---------------- CSR build ----------------
__global__ void count_edges(const void* __restrict__ ei, const void* __restrict__ et,
                            const int* __restrict__ fl, int* __restrict__ cnt, int NEr,
                            int NNr) {
  int e = blockIdx.x * 256 + threadIdx.x;
  if (e >= NEr) return;
  int d = ix_rd(ei, (size_t)NEr + e, fl[4]);
  int r = ix_rd(et, e, fl[5]) & 1;
  if ((unsigned)d >= (unsigned)NNr) return;
  atomicAdd(&cnt[r * NNr + d], 1);
}

__global__ void scan_blocks(const int* __restrict__ in, int* __restrict__ out,
                            int* __restrict__ bsum, int n) {
  __shared__ int sh[256];
  int t = threadIdx.x;
  int base = blockIdx.x * 1024 + t * 4;
  int a[4];
  int s = 0;
#pragma unroll
  for (int i = 0; i < 4; i++) {
    a[i] = (base + i < n) ? in[base + i] : 0;
    s += a[i];
  }
  sh[t] = s;
  __syncthreads();
  for (int d = 1; d < 256; d <<= 1) {
    int v = (t >= d) ? sh[t - d] : 0;
    __syncthreads();
    sh[t] += v;
    __syncthreads();
  }
  int ex = sh[t] - s;
#pragma unroll
  for (int i = 0; i < 4; i++) {
    if (base + i < n) out[base + i] = ex;
    ex += a[i];
  }
  if (t == 255 && bsum) bsum[blockIdx.x] = sh[255];
}

__global__ void scan_add_inv(int* __restrict__ off, const int* __restrict__ bsumsc,
                             const int* __restrict__ cnt, float* __restrict__ inv, int n) {
  int i = blockIdx.x * 256 + threadIdx.x;
  if (i >= n) return;
  off[i] += bsumsc[i >> 10];
  inv[i] = 1.f / fmaxf((float)cnt[i], 1.f);
}

// elist word packs: bits [0,24) = src node id
__global__ void fill_elist(const void* __restrict__ ei, const void* __restrict__ et,
                           const int* __restrict__ fl, const int* __restrict__ off,
                           int* __restrict__ fill, int* __restrict__ elist, int NEr, int NNr) {
  int e = blockIdx.x * 256 + threadIdx.x;
  if (e >= NEr) return;
  int s = ix_rd(ei, e, fl[4]);
  int d = ix_rd(ei, (size_t)NEr + e, fl[4]);
  int r = ix_rd(et, e, fl[5]) & 1;
  if ((unsigned)d >= (unsigned)NNr || (unsigned)s >= (unsigned)NNr) return;
  int idx = r * NNr + d;
  int slot = off[idx] + atomicAdd(&fill[idx], 1);
  elist[slot] = s | ((d & 127) << 24);
}

// ---------------- legacy encoder GEMM (fallback for oversized K) ----------------
__global__ __launch_bounds__(256) void enc_gemm(const void* __restrict__ A,
                                                const void* __restrict__ W,
                                                const void* __restrict__ B,
                                                const int* __restrict__ fl, int fa, int fw,
                                                int fb, bf16* __restrict__ x, int M, int K,
                                                int N, int row0, int col0) {
  __shared__ float Wb[128 * 102];
  __shared__ float bb[128];
  int t = threadIdx.x;
  int stride = (K & 1) ? K : K + 1;
  int fA = fl[fa];
  {
    int fW = fl[fw], fB = fl[fb];
    for (int idx = t; idx < N * K; idx += 256) {
      int j = idx / K, k = idx - j * K;
      Wb[j * stride + k] = in_rd(W, (size_t)j * K + k, fW);
    }
    if (t < N) bb[t] = in_rd(B, t, fB);
  }
  __syncthreads();
  int j = t % N;
  int r = t / N;
  int R = 256 / N;
  int iEnd = blockIdx.x * 64 + 64;
  if (iEnd > M) iEnd = M;
  const float* wrow = &Wb[j * stride];
  if (!fA) {
    const float* Af = (const float*)A;
    for (int i = blockIdx.x * 64 + r; i < iEnd; i += R) {
      const float* a = Af + (size_t)i * K;
      float acc = bb[j];
      for (int k = 0; k < K; k++) acc += a[k] * wrow[k];
      stv(&x[(size_t)(row0 + i) * 128 + col0 + j], lrelu(acc));
    }
  } else {
    const bf16* Ab = (const bf16*)A;
    for (int i = blockIdx.x * 64 + r; i < iEnd; i += R) {
      const bf16* a = Ab + (size_t)i * K;
      float acc = bb[j];
      for (int k = 0; k < K; k++) acc += __bfloat162float(a[k]) * wrow[k];
      stv(&x[(size_t)(row0 + i) * 128 + col0 + j], lrelu(acc));
    }
  }
}

// ================= MFMA GEMMs (bf16 storage, fp32 accumulate) =================
// v_mfma_f32_16x16x32_bf16 fragments (m89/m91-verified C/D mapping):
//   A: lane l holds A[m = l&15][k = (l>>4)*8 + i]
//   B: lane l holds B[k = (l>>4)*8 + i][n = l&15]  (= Wt[n][k], Wt in [out][in] layout)
//   D: lane l reg j -> row = (l>>4)*4 + j, col = l&15

// Fused MFMA encoder: input segs -> LDS bf16 tile -> enc MFMA + lrelu -> LDS ->
// W_in MFMA + lrelu -> global. LDS rows XOR-swizzled (byte ^= (row&7)<<4).
__global__ __launch_bounds__(256) void enc_mfma(
    const void* __restrict__ A0, const void* __restrict__ A1, const void* __restrict__ A2,
    const int* __restrict__ fl, int fi0, int fi1, int fi2, int K0, int K1, int K2,
    const bf16* __restrict__ WbE, const float* __restrict__ biasE,
    const bf16* __restrict__ WbL, const float* __restrict__ bL, bf16* __restrict__ x,
    int M, int row0) {
  __shared__ __align__(16) bf16 Xs[16384];
  int t = threadIdx.x;
  int i0 = blockIdx.x * 128;

  {
    uint4 z = {0u, 0u, 0u, 0u};
#pragma unroll
    for (int i = 0; i < 8; i++) *(uint4*)((char*)Xs + i * 4096 + t * 16) = z;
  }
  __syncthreads();

  const void* As[3] = {A0, A1, A2};
  int Ks_[3] = {K0, K1, K2};
  int fis[3] = {fi0, fi1, fi2};
  int cb = 0;
  for (int s = 0; s < 3; s++) {
    int Ks = Ks_[s];
    if (Ks <= 0) continue;
    int isbf = fl[fis[s]];
    const void* A = As[s];
    int total = 128 * Ks;
    for (int f = t; f < total; f += 256) {
      int row = f / Ks;
      int k = f - row * Ks;
      int gr = i0 + row;
      float v = (gr < M) ? in_rd(A, (size_t)gr * Ks + k, isbf) : 0.f;
      int byte = row * 256 + (cb + k) * 2;
      *(bf16*)((char*)Xs + (byte ^ ((row & 7) << 4))) = __float2bfloat16(v);
    }
    cb += Ks;
  }
  __syncthreads();

  int wv = t >> 6, l = t & 63;
  int lr = l & 15, lg = l >> 4;
  int rbase = (wv >> 1) * 64, cbase = (wv & 1) * 64;
  int ko = lg * 8;
  f32x4 acc[4][4] = {};
#pragma unroll
  for (int ks = 0; ks < 4; ks++) {
    bfv8 bk[4];
#pragma unroll
    for (int cg = 0; cg < 4; cg++)
      bk[cg] = *(const bfv8*)&WbE[(size_t)(cbase + cg * 16 + lr) * 128 + ks * 32 + ko];
    bfv8 af[4];
#pragma unroll
    for (int rg = 0; rg < 4; rg++) {
      int mrow = rbase + rg * 16 + lr;
      int byte = mrow * 256 + (ks * 32 + ko) * 2;
      af[rg] = *(const bfv8*)((const char*)Xs + (byte ^ ((mrow & 7) << 4)));
    }
#pragma unroll
    for (int rg = 0; rg < 4; rg++)
#pragma unroll
      for (int cg = 0; cg < 4; cg++)
        acc[rg][cg] =
            __builtin_amdgcn_mfma_f32_16x16x32_bf16(af[rg], bk[cg], acc[rg][cg], 0, 0, 0);
  }
  __syncthreads();

#pragma unroll
  for (int cg = 0; cg < 4; cg++) {
    int col = cbase + cg * 16 + lr;
    float bv = biasE[col];
#pragma unroll
    for (int rg = 0; rg < 4; rg++) {
      int r0 = rbase + rg * 16 + lg * 4;
#pragma unroll
      for (int j = 0; j < 4; j++) {
        int row = r0 + j;
        int byte = row * 256 + col * 2;
        *(bf16*)((char*)Xs + (byte ^ ((row & 7) << 4))) =
            __float2bfloat16(lrelu(acc[rg][cg][j] + bv));
      }
    }
  }
  __syncthreads();

  f32x4 acc2[4][4] = {};
#pragma unroll
  for (int ks = 0; ks < 4; ks++) {
    bfv8 bk[4];
#pragma unroll
    for (int cg = 0; cg < 4; cg++)
      bk[cg] = *(const bfv8*)&WbL[(size_t)(cbase + cg * 16 + lr) * 128 + ks * 32 + ko];
    bfv8 af[4];
#pragma unroll
    for (int rg = 0; rg < 4; rg++) {
      int mrow = rbase + rg * 16 + lr;
      int byte = mrow * 256 + (ks * 32 + ko) * 2;
      af[rg] = *(const bfv8*)((const char*)Xs + (byte ^ ((mrow & 7) << 4)));
    }
#pragma unroll
    for (int rg = 0; rg < 4; rg++)
#pragma unroll
      for (int cg = 0; cg < 4; cg++)
        acc2[rg][cg] =
            __builtin_amdgcn_mfma_f32_16x16x32_bf16(af[rg], bk[cg], acc2[rg][cg], 0, 0, 0);
  }

#pragma unroll
  for (int cg = 0; cg < 4; cg++) {
    int col = cbase + cg * 16 + lr;
    float bv = bL[col];
#pragma unroll
    for (int rg = 0; rg < 4; rg++) {
      int r0 = i0 + rbase + rg * 16 + lg * 4;
#pragma unroll
      for (int j = 0; j < 4; j++) {
        int row = r0 + j;
        if (row < M)
          x[(size_t)(row0 + row) * 128 + col] = __float2bfloat16(lrelu(acc2[rg][cg][j] + bv));
      }
    }
  }
}

// Out = lrelu(A @ Wb^T + bias); fallback-path linear
__global__ __launch_bounds__(256) void mfma_lin(const bf16* __restrict__ A,
                                                const bf16* __restrict__ Wb,
                                                const float* __restrict__ bias,
                                                bf16* __restrict__ Out, int M) {
  int t = threadIdx.x;
  int wv = t >> 6, l = t & 63;
  int lr = l & 15, lg = l >> 4;
  int i0 = blockIdx.x * 128;
  int rbase = (wv >> 1) * 64;
  int cbase = (wv & 1) * 64;
  int ko = lg * 8;

  size_t rowoff[4];
#pragma unroll
  for (int rg = 0; rg < 4; rg++) {
    int row = i0 + rbase + rg * 16 + lr;
    if (row > M - 1) row = M - 1;
    rowoff[rg] = (size_t)row * 128;
  }

  bfv8 bfr[4][4];
#pragma unroll
  for (int cg = 0; cg < 4; cg++)
#pragma unroll
    for (int ks = 0; ks < 4; ks++)
      bfr[cg][ks] = *(const bfv8*)&Wb[(size_t)(cbase + cg * 16 + lr) * 128 + ks * 32 + ko];

  f32x4 acc[4][4] = {};
#pragma unroll
  for (int ks = 0; ks < 4; ks++) {
    bfv8 af[4];
#pragma unroll
    for (int rg = 0; rg < 4; rg++) af[rg] = *(const bfv8*)&A[rowoff[rg] + ks * 32 + ko];
#pragma unroll
    for (int rg = 0; rg < 4; rg++)
#pragma unroll
      for (int cg = 0; cg < 4; cg++)
        acc[rg][cg] =
            __builtin_amdgcn_mfma_f32_16x16x32_bf16(af[rg], bfr[cg][ks], acc[rg][cg], 0, 0, 0);
  }

#pragma unroll
  for (int cg = 0; cg < 4; cg++) {
    int col = cbase + cg * 16 + lr;
    float bv = bias[col];
#pragma unroll
    for (int rg = 0; rg < 4; rg++) {
      int row0 = i0 + rbase + rg * 16 + lg * 4;
#pragma unroll
      for (int j = 0; j < 4; j++) {
        int row = row0 + j;
        if (row < M) Out[(size_t)row * 128 + col] = __float2bfloat16(lrelu(acc[rg][cg][j] + bv));
      }
    }
  }
}

// Fused RGCN conv, 16-row blocks: Out = X@root + mean_r0@rw0 + mean_r1@rw1 + bias.
// Both rels in one 16KB fp32 LDS tile (vrows 0-15 rel0, 16-31 rel1).
// The block's CSR elist slices (contiguous per rel) are STAGED INTO LDS first, so the
// gather walk's edge-word reads are lgkmcnt ops - the per-iteration elist->X vmcnt
// round-trip (R5-R7's serializer: ~22us/block, depth~1) is gone. 2 cursors/thread
// (same node, both rels) walked jointly, branch-free clamped. 12.5K blocks + 20KB LDS +
// low VGPR -> 6-8 blocks/CU resident to cover remaining depth-1 X-wait latency.
// TAIL=true fuses lrelu(conv@Wo1^T+bO1)@Wo2^T+bo2 -> out2.
#define ELCAP 1024
template <bool TAIL>
__global__ __launch_bounds__(256, 6) void mfma_conv_f(
    const bf16* __restrict__ X, const int* __restrict__ off, const int* __restrict__ cnt,
    const int* __restrict__ elist, const float* __restrict__ inv,
    const bf16* __restrict__ WB, const float* __restrict__ bias, bf16* __restrict__ Out,
    const bf16* __restrict__ Wo1B, const float* __restrict__ bO1,
    const float* __restrict__ Wo2, const float* __restrict__ bo2,
    float* __restrict__ out2, int M, int NNr, int NEr) {
  __shared__ __align__(16) float At[32 * 128];
  __shared__ int eLs[ELCAP];
  int t = threadIdx.x;
  int wv = t >> 6, l = t & 63;
  int lr = l & 15, lg = l >> 4;
  int i0 = blockIdx.x * 16;
  int cbase = wv * 32;
  int ko = lg * 8;

  int iend = (i0 + 16 < M) ? i0 + 16 : M;
  int e0a = off[i0];
  int n0 = off[iend - 1] + cnt[iend - 1] - e0a;
  int e0b = off[NNr + i0];
  int n1 = off[NNr + iend - 1] + cnt[NNr + iend - 1] - e0b;
  int staged = n0 + n1 < ELCAP ? n0 + n1 : ELCAP;

  // ---- stage elist slices to LDS (coalesced) ----
  for (int k = t; k < staged; k += 256)
    eLs[k] = (k < n0) ? elist[e0a + k] : elist[e0b + (k - n0)];

  // per-thread cursors: node = i0 + (t>>4), cursor 0 = rel0, cursor 1 = rel1
  int grp = t >> 4;
  int c8 = (t & 15) * 8;
  int node = i0 + grp;
  bool ok = node < M;
  int stc[2], dgc[2], lbase[2];
  {
    int idx0 = node, idx1 = NNr + node;
    stc[0] = ok ? off[idx0] : 0;
    dgc[0] = ok ? cnt[idx0] : 0;
    stc[1] = ok ? off[idx1] : 0;
    dgc[1] = ok ? cnt[idx1] : 0;
    lbase[0] = stc[0] - e0a;
    lbase[1] = n0 + (stc[1] - e0b);
  }
  __syncthreads();

  // ---- joint 2-cursor walk; edge words from LDS (global fallback past ELCAP) ----
  {
    int dmax = dgc[0] > dgc[1] ? dgc[0] : dgc[1];
    float s[2][8] = {};

    auto srcof = [&](int pn, int e) -> size_t {
      int ec = e < dgc[pn] - 1 ? e : dgc[pn] - 1;
      ec = ec < 0 ? 0 : ec;
      int lidx = lbase[pn] + ec;
      int w;
      if (lidx < staged) {
        w = eLs[lidx];
      } else {
        int g = stc[pn] + ec;
        g = g < NEr - 1 ? g : NEr - 1;
        w = elist[g];
      }
      return (size_t)(w & 0xFFFFFF) * 128 + c8;
    };

    bfv8 v0[2], v1[2];
#pragma unroll
    for (int pn = 0; pn < 2; pn++) v0[pn] = *(const bfv8*)&X[srcof(pn, 0)];
#pragma unroll
    for (int pn = 0; pn < 2; pn++) v1[pn] = *(const bfv8*)&X[srcof(pn, 1)];

    for (int e = 0; e < dmax; e++) {
      bfv8 v2[2];
#pragma unroll
      for (int pn = 0; pn < 2; pn++) v2[pn] = *(const bfv8*)&X[srcof(pn, e + 2)];
#pragma unroll
      for (int pn = 0; pn < 2; pn++) {
        float msk = e < dgc[pn] ? 1.f : 0.f;
#pragma unroll
        for (int j = 0; j < 8; j++) s[pn][j] += msk * __bfloat162float(v0[pn][j]);
      }
#pragma unroll
      for (int pn = 0; pn < 2; pn++) {
        v0[pn] = v1[pn];
        v1[pn] = v2[pn];
      }
    }
#pragma unroll
    for (int pn = 0; pn < 2; pn++) {
      int vr = pn * 16 + grp;
      int sw = (vr & 7) << 4;
      int lb = vr * 512 + c8 * 4;
      *(float4*)((char*)At + (lb ^ sw)) = make_float4(s[pn][0], s[pn][1], s[pn][2], s[pn][3]);
      *(float4*)((char*)At + ((lb + 16) ^ sw)) =
          make_float4(s[pn][4], s[pn][5], s[pn][6], s[pn][7]);
    }
  }

  // row clamp and inv scales (single 16-row group per wave)
  size_t rowoff;
  float iv0, iv1;
  {
    int row = i0 + lr;
    int rc = row < M ? row : M - 1;
    rowoff = (size_t)rc * 128;
    iv0 = row < M ? inv[row] : 0.f;
    iv1 = row < M ? inv[NNr + row] : 0.f;
  }

  f32x4 acc[2] = {};

  // ---- seg 0: X @ root from global (overlaps gather LDS-store latency) ----
#pragma unroll
  for (int ks = 0; ks < 4; ks++) {
    bfv8 bk[2];
#pragma unroll
    for (int cg = 0; cg < 2; cg++)
      bk[cg] = *(const bfv8*)&WB[(size_t)(cbase + cg * 16 + lr) * 128 + ks * 32 + ko];
    bfv8 af = *(const bfv8*)&X[rowoff + ks * 32 + ko];
#pragma unroll
    for (int cg = 0; cg < 2; cg++)
      acc[cg] = __builtin_amdgcn_mfma_f32_16x16x32_bf16(af, bk[cg], acc[cg], 0, 0, 0);
  }
  __syncthreads();

  // ---- rel-0 / rel-1 MFMA from LDS (inv-scaled, cvt to bf16) ----
#pragma unroll
  for (int r = 0; r < 2; r++) {
    const bf16* Wb = WB + 16384 * (1 + r);
    float iv = r ? iv1 : iv0;
#pragma unroll
    for (int ks = 0; ks < 4; ks++) {
      bfv8 bk[2];
#pragma unroll
      for (int cg = 0; cg < 2; cg++)
        bk[cg] = *(const bfv8*)&Wb[(size_t)(cbase + cg * 16 + lr) * 128 + ks * 32 + ko];
      int mrow = r * 16 + lr;
      int lb = mrow * 512 + ks * 128 + ko * 4;
      int sw = (mrow & 7) << 4;
      float4 f0 = *(const float4*)((const char*)At + (lb ^ sw));
      float4 f1 = *(const float4*)((const char*)At + ((lb + 16) ^ sw));
      bfv8 a;
      a[0] = (__bf16)(f0.x * iv); a[1] = (__bf16)(f0.y * iv);
      a[2] = (__bf16)(f0.z * iv); a[3] = (__bf16)(f0.w * iv);
      a[4] = (__bf16)(f1.x * iv); a[5] = (__bf16)(f1.y * iv);
      a[6] = (__bf16)(f1.z * iv); a[7] = (__bf16)(f1.w * iv);
#pragma unroll
      for (int cg = 0; cg < 2; cg++)
        acc[cg] = __builtin_amdgcn_mfma_f32_16x16x32_bf16(a, bk[cg], acc[cg], 0, 0, 0);
    }
  }

  if (!TAIL) {
#pragma unroll
    for (int cg = 0; cg < 2; cg++) {
      int col = cbase + cg * 16 + lr;
      float bv = bias[col];
#pragma unroll
      for (int j = 0; j < 4; j++) {
        int row = i0 + lg * 4 + j;
        if (row < M) Out[(size_t)row * 128 + col] = __float2bfloat16(acc[cg][j] + bv);
      }
    }
  } else {
    // ---- fused tail ----
    __syncthreads();  // all At reads done before overwrite
#pragma unroll
    for (int cg = 0; cg < 2; cg++) {
      int col = cbase + cg * 16 + lr;
      float bv = bias[col];
#pragma unroll
      for (int j = 0; j < 4; j++) {
        int r16 = lg * 4 + j;
        int byte = r16 * 256 + col * 2;
        *(bf16*)((char*)At + (byte ^ ((r16 & 7) << 4))) = __float2bfloat16(acc[cg][j] + bv);
      }
    }
    __syncthreads();

    // z = lrelu(y @ Wo1^T + bO1), 16 rows x 128 cols
    f32x4 acc2[2] = {};
#pragma unroll
    for (int ks = 0; ks < 4; ks++) {
      bfv8 bk[2];
#pragma unroll
      for (int cg = 0; cg < 2; cg++)
        bk[cg] = *(const bfv8*)&Wo1B[(size_t)(cbase + cg * 16 + lr) * 128 + ks * 32 + ko];
      int byte = lr * 256 + (ks * 32 + ko) * 2;
      bfv8 af = *(const bfv8*)((const char*)At + (byte ^ ((lr & 7) << 4)));
#pragma unroll
      for (int cg = 0; cg < 2; cg++)
        acc2[cg] = __builtin_amdgcn_mfma_f32_16x16x32_bf16(af, bk[cg], acc2[cg], 0, 0, 0);
    }
#pragma unroll
    for (int cg = 0; cg < 2; cg++) {
      int col = cbase + cg * 16 + lr;
      float bv = bO1[col];
#pragma unroll
      for (int j = 0; j < 4; j++) {
        int r16 = lg * 4 + j;
        *(bf16*)((char*)At + 8192 + r16 * 256 + col * 2) =
            __float2bfloat16(lrelu(acc2[cg][j] + bv));
      }
    }
    __syncthreads();

    // out2[row] = z_row @ Wo2^T + bo2; 16 threads/row, 8 cols each, shuffle-reduce
    int row = t >> 4, seg = t & 15;
    const bf16* zr = (const bf16*)((const char*)At + 8192 + row * 256 + seg * 16);
    float p0 = 0.f, p1 = 0.f;
#pragma unroll
    for (int q = 0; q < 8; q++) {
      float xv = __bfloat162float(zr[q]);
      int col = seg * 8 + q;
      p0 += xv * Wo2[col];
      p1 += xv * Wo2[128 + col];
    }
#pragma unroll
    for (int o = 8; o; o >>= 1) {
      p0 += __shfl_down(p0, o, 16);
      p1 += __shfl_down(p1, o, 16);
    }
    int grow = i0 + row;
    if (seg == 0 && grow < M) {
      out2[(size_t)grow * 2] = p0 + bo2[0];
      out2[(size_t)grow * 2 + 1] = p1 + bo2[1];
    }
  }
}

// ---------------- pipeline (bf16 storage, MFMA everywhere, fused ends) ----------------
static void run_pipeline(void* const* d_in, const int* S, float* out, char* ws,
                         int NUr, int NTr, int NEr, int dDes, int dNum, int dCat, int dTw,
                         hipStream_t stream) {
  const int NNr = NUr + NTr;
  const size_t xbytes = (size_t)NNr * 128 * 2;

  bf16* xa = (bf16*)ws;
  bf16* xb = (bf16*)(ws + xbytes);
  char* p = ws + 2 * xbytes;
  int* cnt = (int*)p;      p += (size_t)2 * NNr * 4;
  int* fill = (int*)p;     p += (size_t)2 * NNr * 4;  // contiguous with cnt
  int* off = (int*)p;      p += (size_t)2 * NNr * 4;
  int* bsum = (int*)p;     p += 2048 * 4;             // contiguous with bsumsc
  int* bsumsc = (int*)p;   p += 2048 * 4;
  float* inv = (float*)p;  p += (size_t)2 * NNr * 4;
  int* elist = (int*)p;    p += (size_t)NEr * 4;
  float* pw = (float*)p;   p += (size_t)PW_TOTAL * 4;
  int* flags = (int*)p;

  // ---- format probes: one launch ----
  ProbeArgs pa;
  for (int i = 0; i < 23; i++) {
    int src = (i == 22) ? 21 : i;  // b_o2 (2 elems) inherits W_o2's dtype
    pa.p[i] = d_in[src];
    if (i == 4) {
      pa.mode[i] = 1;
      pa.s[i] = NEr < 256 ? NEr : 256;
    } else if (i == 5) {
      pa.mode[i] = 1;
      int s2 = NEr / 2 < 256 ? NEr / 2 : 256;
      pa.s[i] = s2 < 1 ? 1 : s2;
    } else {
      pa.mode[i] = 0;
      int s = S[src] / 2;
      if (s > 256) s = 256;
      if (s < 1) s = 1;
      pa.s[i] = s;
    }
  }
  detect_all<<<23, 256, 0, stream>>>(pa, flags);
  prep_weights<<<(PW_W_TOTAL + 255) / 256, 256, 0, stream>>>(
      d_in[14], d_in[15], d_in[16], d_in[17], d_in[18], d_in[19], d_in[20], d_in[21],
      d_in[22], flags, pw);
  prep_enc<<<129, 256, 0, stream>>>(d_in[6], d_in[7], d_in[8], d_in[9], d_in[10], d_in[11],
                                    d_in[12], d_in[13], flags, dDes, dNum, dCat, dTw, pw);

  const float* bIn = pw + 81920;
  const float* rbp = pw + 82048;
  const float* bO1 = pw + 82176;
  const float* Wo2p = pw + 82304;
  const float* bo2p = pw + 82560;
  const bf16* WinB = (const bf16*)(pw + BF_BASE);
  const bf16* Wo1B = (const bf16*)(pw + BF_BASE + 8192);
  const bf16* ConvB = (const bf16*)(pw + BF_BASE + 16384);  // rootB, rwB0, rwB1
  const bf16* EncU = (const bf16*)(pw + ENC_BASE);
  const bf16* EncT = (const bf16*)(pw + ENC_BASE + 8192);
  const float* bU = pw + ENC_BASE + 16384;
  const float* bT = bU + 128;

  const void* ei = d_in[4];
  const void* et = d_in[5];
  const int nb1 = (2 * NNr + 1023) / 1024;

  // ---- CSR build ----
  zero_ints<<<(4 * NNr + 255) / 256, 256, 0, stream>>>(cnt, 4 * NNr);
  zero_ints<<<16, 256, 0, stream>>>(bsum, 4096);
  count_edges<<<(NEr + 255) / 256, 256, 0, stream>>>(ei, et, flags, cnt, NEr, NNr);
  scan_blocks<<<nb1, 256, 0, stream>>>(cnt, off, bsum, 2 * NNr);
  scan_blocks<<<1, 256, 0, stream>>>(bsum, bsumsc, nullptr, nb1);
  scan_add_inv<<<(2 * NNr + 255) / 256, 256, 0, stream>>>(off, bsumsc, cnt, inv, 2 * NNr);
  fill_elist<<<(NEr + 255) / 256, 256, 0, stream>>>(ei, et, flags, off, fill, elist, NEr, NNr);

  // ---- encoders (fused with W_in) -> xb ----
  if (dDes + dNum + dCat <= 128 && dTw <= 128) {
    enc_mfma<<<(NUr + 127) / 128, 256, 0, stream>>>(d_in[0], d_in[2], d_in[3], flags, 0, 2, 3,
                                                    dDes, dNum, dCat, EncU, bU, WinB, bIn, xb,
                                                    NUr, 0);
    enc_mfma<<<(NTr + 127) / 128, 256, 0, stream>>>(d_in[1], nullptr, nullptr, flags, 1, 1, 1,
                                                    dTw, 0, 0, EncT, bT, WinB, bIn, xb, NTr,
                                                    NUr);
  } else {
    enc_gemm<<<(NUr + 63) / 64, 256, 0, stream>>>(d_in[0], d_in[6], d_in[7], flags, 0, 6, 7,
                                                  xa, NUr, dDes, 64, 0, 0);
    enc_gemm<<<(NUr + 63) / 64, 256, 0, stream>>>(d_in[2], d_in[8], d_in[9], flags, 2, 8, 9,
                                                  xa, NUr, dNum, 32, 0, 64);
    enc_gemm<<<(NUr + 63) / 64, 256, 0, stream>>>(d_in[3], d_in[10], d_in[11], flags, 3, 10,
                                                  11, xa, NUr, dCat, 32, 0, 96);
    enc_gemm<<<(NTr + 63) / 64, 256, 0, stream>>>(d_in[1], d_in[12], d_in[13], flags, 1, 12,
                                                  13, xa, NTr, dTw, 128, NUr, 0);
    mfma_lin<<<(NNr + 127) / 128, 256, 0, stream>>>(xa, WinB, bIn, xb, NNr);
  }

  const int mt16 = (NNr + 15) / 16;
  mfma_conv_f<false><<<mt16, 256, 0, stream>>>(xb, off, cnt, elist, inv, ConvB, rbp, xa,
                                               nullptr, nullptr, nullptr, nullptr, nullptr,
                                               NNr, NNr, NEr);
  mfma_conv_f<true><<<mt16, 256, 0, stream>>>(xa, off, cnt, elist, inv, ConvB, rbp, nullptr,
                                              Wo1B, bO1, Wo2p, bo2p, out, NNr, NNr, NEr);
}

extern "C" void kernel_launch(void* const* d_in, const int* in_sizes, int n_in,
                              void* d_out, int out_size, void* d_ws, size_t ws_size,
                              hipStream_t stream) {
  float* out = (float*)d_out;
  char* ws = (char*)d_ws;

  auto signal = [&](int k) {
    sig_fill<<<(out_size + 255) / 256, 256, 0, stream>>>(out, out_size, (float)(200 + k));
  };

  if (n_in != 23) { signal(1); return; }
  const int* S = in_sizes;
  if (S[7] != 64 || S[9] != 32 || S[11] != 32 || S[13] != 128) { signal(2); return; }
  if (S[15] != 128) { signal(3); return; }
  if (S[6] % 64 || S[8] % 32 || S[10] % 32 || S[12] % 128) { signal(4); return; }
  int dDes = S[6] / 64, dNum = S[8] / 32, dCat = S[10] / 32, dTw = S[12] / 128;
  if (dDes <= 0 || dTw <= 0 || S[0] % dDes || S[1] % dTw) { signal(5); return; }
  if (dDes > 101 || dNum > 101 || dCat > 101 || dTw > 101) { signal(4); return; }
  int NUr = S[0] / dDes, NTr = S[1] / dTw, NNr = NUr + NTr, NEr = S[5];
  if (S[2] != NUr * dNum || S[3] != NUr * dCat) { signal(5); return; }
  if (S[4] != 2 * NEr || NEr < 1024) { signal(6); return; }
  if (NNr >= (1 << 24)) { signal(6); return; }  // elist src-packing limit
  if (S[14] != 16384 || S[16] != 32768 || S[17] != 16384 || S[18] != 128 ||
      S[19] != 16384 || S[20] != 128 || S[21] != 256 || S[22] != 2) { signal(7); return; }
  if (out_size != NNr * 2) { signal(8); return; }

  const size_t smallBytes = (size_t)4 * ((size_t)2 * NNr * 4) + 2 * 2048 * 4 +
                            (size_t)NEr * 4 + (size_t)PW_TOTAL * 4 + 512;
  const size_t need = 2 * (size_t)NNr * 128 * 2 + smallBytes;

  if (ws_size >= need) {
    run_pipeline(d_in, S, out, ws, NUr, NTr, NEr, dDes, dNum, dCat, dTw, stream);
  } else {
    signal(9);
  }
}

// Round 9
// 540.393 us; speedup vs baseline: 1.1991x; 1.1991x over previous
//
#include <hip/hip_runtime.h>
#include <hip/hip_bf16.h>

typedef __hip_bfloat16 bf16;

typedef __bf16 bfv8 __attribute__((ext_vector_type(8)));
typedef float f32x4 __attribute__((ext_vector_type(4)));

__device__ __forceinline__ float lrelu(float x) { return x > 0.f ? x : 0.01f * x; }

__device__ __forceinline__ float ldv(float v) { return v; }
__device__ __forceinline__ float ldv(bf16 v) { return __bfloat162float(v); }
__device__ __forceinline__ void stv(float* p, float v) { *p = v; }
__device__ __forceinline__ void stv(bf16* p, float v) { *p = __float2bfloat16(v); }

__device__ __forceinline__ float in_rd(const void* p, size_t i, int isbf) {
  return isbf ? __bfloat162float(((const bf16*)p)[i]) : ((const float*)p)[i];
}
__device__ __forceinline__ int ix_rd(const void* p, size_t i, int is64) {
  return is64 ? (int)((const long long*)p)[i] : ((const int*)p)[i];
}

// ---------------- fused per-array format probe: one launch, 23 blocks ----------------
struct ProbeArgs {
  const void* p[23];
  int s[23];
  int mode[23];
};

__global__ void detect_all(ProbeArgs a, int* __restrict__ flags) {
  __shared__ int sh[256];
  int b = blockIdx.x;
  const unsigned int* w = (const unsigned int*)a.p[b];
  int s = a.s[b], mode = a.mode[b];
  int t = threadIdx.x;
  int c = 0;
  if (t < s) {
    if (mode == 0) {
      unsigned int v = w[t];
      int e = (v >> 7) & 0xFF;
      c = (e >= 100 && e <= 140) ? 1 : 0;
    } else {
      c = (w[2 * t + 1] == 0u) ? 1 : 0;
    }
  }
  sh[t] = c;
  __syncthreads();
  for (int d = 128; d; d >>= 1) {
    if (t < d) sh[t] += sh[t + d];
    __syncthreads();
  }
  if (t == 0) flags[b] = (mode == 0) ? (sh[0] * 10 >= 7 * s) : (sh[0] * 10 >= 9 * s);
}

// ---------------- weight prep ----------------
// fp32 region (floats): [0,16384) W_inT [k,n]; [16384,32768) W_o1T [k,n]; [32768,49152) root;
// [49152,81920) rw; [81920] b_in; [82048] rgcn_bias; [82176] b_o1; [82304] W_o2; [82560] b_o2
// bf16 region (float index BF_BASE): 5x [128][128] bf16 [out][in]:
//   m=0 WinB; m=1 Wo1B; m=2 rootB; m=3 rwB0; m=4 rwB1
// ENC region (float index ENC_BASE): EncU bf16[128][128]; EncT bf16[128][128]; biasU; biasT
#define PW_F32 82562
#define BF_BASE 82564
#define PW_W_TOTAL (BF_BASE + 5 * 8192)
#define ENC_BASE PW_W_TOTAL
#define PW_TOTAL (ENC_BASE + 16384 + 256)
__global__ void prep_weights(const void* Win, const void* bin, const void* rw,
                             const void* root, const void* rb, const void* Wo1,
                             const void* bo1, const void* Wo2, const void* bo2,
                             const int* __restrict__ fl, float* __restrict__ pw) {
  int i = blockIdx.x * 256 + threadIdx.x;
  if (i >= PW_W_TOTAL) return;
  if (i < 16384) {
    int k = i >> 7, o = i & 127;
    pw[i] = in_rd(Win, (size_t)o * 128 + k, fl[14]);
  } else if (i < 32768) {
    int j = i - 16384;
    int k = j >> 7, o = j & 127;
    pw[i] = in_rd(Wo1, (size_t)o * 128 + k, fl[19]);
  } else if (i < 49152) {
    pw[i] = in_rd(root, i - 32768, fl[17]);
  } else if (i < 81920) {
    pw[i] = in_rd(rw, i - 49152, fl[16]);
  } else if (i < 82048) {
    pw[i] = in_rd(bin, i - 81920, fl[15]);
  } else if (i < 82176) {
    pw[i] = in_rd(rb, i - 82048, fl[18]);
  } else if (i < 82304) {
    pw[i] = in_rd(bo1, i - 82176, fl[20]);
  } else if (i < 82560) {
    pw[i] = in_rd(Wo2, i - 82304, fl[21]);
  } else if (i < PW_F32) {
    pw[i] = in_rd(bo2, i - 82560, fl[22]);
  } else if (i >= BF_BASE) {
    int j = i - BF_BASE;
    bf16* bw = (bf16*)(pw + BF_BASE);
#pragma unroll
    for (int q = 0; q < 2; q++) {
      int u = 2 * j + q;
      int m = u >> 14, r = u & 16383;
      int n = r >> 7, k = r & 127;
      float v;
      if (m == 0) v = in_rd(Win, (size_t)n * 128 + k, fl[14]);
      else if (m == 1) v = in_rd(Wo1, (size_t)n * 128 + k, fl[19]);
      else if (m == 2) v = in_rd(root, (size_t)k * 128 + n, fl[17]);
      else v = in_rd(rw, (size_t)(m - 3) * 16384 + (size_t)k * 128 + n, fl[16]);
      bw[u] = __float2bfloat16(v);
    }
  }
}

// Builds fused encoder weights/biases.
__global__ void prep_enc(const void* Wd, const void* bd, const void* Wn, const void* bn,
                         const void* Wc, const void* bc, const void* Wt, const void* bt,
                         const int* __restrict__ fl, int dDes, int dNum, int dCat, int dTw,
                         float* __restrict__ pw) {
  int i = blockIdx.x * 256 + threadIdx.x;
  bf16* e = (bf16*)(pw + ENC_BASE);
  float* bU = pw + ENC_BASE + 16384;
  float* bT = bU + 128;
  if (i < 16384) {
    int n = i >> 7, k = i & 127;
    float v = 0.f;
    if (n < 64) {
      if (k < dDes) v = in_rd(Wd, (size_t)n * dDes + k, fl[6]);
    } else if (n < 96) {
      int kk = k - dDes;
      if (kk >= 0 && kk < dNum) v = in_rd(Wn, (size_t)(n - 64) * dNum + kk, fl[8]);
    } else {
      int kk = k - dDes - dNum;
      if (kk >= 0 && kk < dCat) v = in_rd(Wc, (size_t)(n - 96) * dCat + kk, fl[10]);
    }
    e[i] = __float2bfloat16(v);
  } else if (i < 32768) {
    int j = i - 16384;
    int n = j >> 7, k = j & 127;
    float v = (k < dTw) ? in_rd(Wt, (size_t)n * dTw + k, fl[12]) : 0.f;
    e[i] = __float2bfloat16(v);
  } else if (i < 32896) {
    int j = i - 32768;
    bU[j] = (j < 64) ? in_rd(bd, j, fl[7])
                     : (j < 96) ? in_rd(bn, j - 64, fl[9]) : in_rd(bc, j - 96, fl[11]);
  } else if (i < 33024) {
    bT[i - 32896] = in_rd(bt, i - 32896, fl[13]);
  }
}

// ---------------- utilities ----------------
__global__ void sig_fill(float* __restrict__ p, int n, float v) {
  int i = blockIdx.x * 256 + threadIdx.x;
  if (i < n) p[i] = v;
}
__global__ void zero_ints(int* __restrict__ p, int n) {
  int i = blockIdx.x * 256 + threadIdx.x;
  if (i < n) p[i] = 0;
}

// ---------------- CSR build ----------------
__global__ void count_edges(const void* __restrict__ ei, const void* __restrict__ et,
                            const int* __restrict__ fl, int* __restrict__ cnt, int NEr,
                            int NNr) {
  int e = blockIdx.x * 256 + threadIdx.x;
  if (e >= NEr) return;
  int d = ix_rd(ei, (size_t)NEr + e, fl[4]);
  int r = ix_rd(et, e, fl[5]) & 1;
  if ((unsigned)d >= (unsigned)NNr) return;
  atomicAdd(&cnt[r * NNr + d], 1);
}

__global__ void scan_blocks(const int* __restrict__ in, int* __restrict__ out,
                            int* __restrict__ bsum, int n) {
  __shared__ int sh[256];
  int t = threadIdx.x;
  int base = blockIdx.x * 1024 + t * 4;
  int a[4];
  int s = 0;
#pragma unroll
  for (int i = 0; i < 4; i++) {
    a[i] = (base + i < n) ? in[base + i] : 0;
    s += a[i];
  }
  sh[t] = s;
  __syncthreads();
  for (int d = 1; d < 256; d <<= 1) {
    int v = (t >= d) ? sh[t - d] : 0;
    __syncthreads();
    sh[t] += v;
    __syncthreads();
  }
  int ex = sh[t] - s;
#pragma unroll
  for (int i = 0; i < 4; i++) {
    if (base + i < n) out[base + i] = ex;
    ex += a[i];
  }
  if (t == 255 && bsum) bsum[blockIdx.x] = sh[255];
}

__global__ void scan_add_inv(int* __restrict__ off, const int* __restrict__ bsumsc,
                             const int* __restrict__ cnt, float* __restrict__ inv, int n) {
  int i = blockIdx.x * 256 + threadIdx.x;
  if (i >= n) return;
  off[i] += bsumsc[i >> 10];
  inv[i] = 1.f / fmaxf((float)cnt[i], 1.f);
}

// elist word packs: bits [0,24) = src node id
__global__ void fill_elist(const void* __restrict__ ei, const void* __restrict__ et,
                           const int* __restrict__ fl, const int* __restrict__ off,
                           int* __restrict__ fill, int* __restrict__ elist, int NEr, int NNr) {
  int e = blockIdx.x * 256 + threadIdx.x;
  if (e >= NEr) return;
  int s = ix_rd(ei, e, fl[4]);
  int d = ix_rd(ei, (size_t)NEr + e, fl[4]);
  int r = ix_rd(et, e, fl[5]) & 1;
  if ((unsigned)d >= (unsigned)NNr || (unsigned)s >= (unsigned)NNr) return;
  int idx = r * NNr + d;
  int slot = off[idx] + atomicAdd(&fill[idx], 1);
  elist[slot] = s | ((d & 127) << 24);
}

// ---------------- legacy encoder GEMM (fallback for oversized K) ----------------
__global__ __launch_bounds__(256) void enc_gemm(const void* __restrict__ A,
                                                const void* __restrict__ W,
                                                const void* __restrict__ B,
                                                const int* __restrict__ fl, int fa, int fw,
                                                int fb, bf16* __restrict__ x, int M, int K,
                                                int N, int row0, int col0) {
  __shared__ float Wb[128 * 102];
  __shared__ float bb[128];
  int t = threadIdx.x;
  int stride = (K & 1) ? K : K + 1;
  int fA = fl[fa];
  {
    int fW = fl[fw], fB = fl[fb];
    for (int idx = t; idx < N * K; idx += 256) {
      int j = idx / K, k = idx - j * K;
      Wb[j * stride + k] = in_rd(W, (size_t)j * K + k, fW);
    }
    if (t < N) bb[t] = in_rd(B, t, fB);
  }
  __syncthreads();
  int j = t % N;
  int r = t / N;
  int R = 256 / N;
  int iEnd = blockIdx.x * 64 + 64;
  if (iEnd > M) iEnd = M;
  const float* wrow = &Wb[j * stride];
  if (!fA) {
    const float* Af = (const float*)A;
    for (int i = blockIdx.x * 64 + r; i < iEnd; i += R) {
      const float* a = Af + (size_t)i * K;
      float acc = bb[j];
      for (int k = 0; k < K; k++) acc += a[k] * wrow[k];
      stv(&x[(size_t)(row0 + i) * 128 + col0 + j], lrelu(acc));
    }
  } else {
    const bf16* Ab = (const bf16*)A;
    for (int i = blockIdx.x * 64 + r; i < iEnd; i += R) {
      const bf16* a = Ab + (size_t)i * K;
      float acc = bb[j];
      for (int k = 0; k < K; k++) acc += __bfloat162float(a[k]) * wrow[k];
      stv(&x[(size_t)(row0 + i) * 128 + col0 + j], lrelu(acc));
    }
  }
}

// ================= MFMA GEMMs (bf16 storage, fp32 accumulate) =================
// v_mfma_f32_16x16x32_bf16 fragments (m89/m91-verified C/D mapping):
//   A: lane l holds A[m = l&15][k = (l>>4)*8 + i]
//   B: lane l holds B[k = (l>>4)*8 + i][n = l&15]  (= Wt[n][k], Wt in [out][in] layout)
//   D: lane l reg j -> row = (l>>4)*4 + j, col = l&15

// Fused MFMA encoder: input segs -> LDS bf16 tile -> enc MFMA + lrelu -> LDS ->
// W_in MFMA + lrelu -> global. LDS rows XOR-swizzled (byte ^= (row&7)<<4).
__global__ __launch_bounds__(256) void enc_mfma(
    const void* __restrict__ A0, const void* __restrict__ A1, const void* __restrict__ A2,
    const int* __restrict__ fl, int fi0, int fi1, int fi2, int K0, int K1, int K2,
    const bf16* __restrict__ WbE, const float* __restrict__ biasE,
    const bf16* __restrict__ WbL, const float* __restrict__ bL, bf16* __restrict__ x,
    int M, int row0) {
  __shared__ __align__(16) bf16 Xs[16384];
  int t = threadIdx.x;
  int i0 = blockIdx.x * 128;

  {
    uint4 z = {0u, 0u, 0u, 0u};
#pragma unroll
    for (int i = 0; i < 8; i++) *(uint4*)((char*)Xs + i * 4096 + t * 16) = z;
  }
  __syncthreads();

  const void* As[3] = {A0, A1, A2};
  int Ks_[3] = {K0, K1, K2};
  int fis[3] = {fi0, fi1, fi2};
  int cb = 0;
  for (int s = 0; s < 3; s++) {
    int Ks = Ks_[s];
    if (Ks <= 0) continue;
    int isbf = fl[fis[s]];
    const void* A = As[s];
    int total = 128 * Ks;
    for (int f = t; f < total; f += 256) {
      int row = f / Ks;
      int k = f - row * Ks;
      int gr = i0 + row;
      float v = (gr < M) ? in_rd(A, (size_t)gr * Ks + k, isbf) : 0.f;
      int byte = row * 256 + (cb + k) * 2;
      *(bf16*)((char*)Xs + (byte ^ ((row & 7) << 4))) = __float2bfloat16(v);
    }
    cb += Ks;
  }
  __syncthreads();

  int wv = t >> 6, l = t & 63;
  int lr = l & 15, lg = l >> 4;
  int rbase = (wv >> 1) * 64, cbase = (wv & 1) * 64;
  int ko = lg * 8;
  f32x4 acc[4][4] = {};
#pragma unroll
  for (int ks = 0; ks < 4; ks++) {
    bfv8 bk[4];
#pragma unroll
    for (int cg = 0; cg < 4; cg++)
      bk[cg] = *(const bfv8*)&WbE[(size_t)(cbase + cg * 16 + lr) * 128 + ks * 32 + ko];
    bfv8 af[4];
#pragma unroll
    for (int rg = 0; rg < 4; rg++) {
      int mrow = rbase + rg * 16 + lr;
      int byte = mrow * 256 + (ks * 32 + ko) * 2;
      af[rg] = *(const bfv8*)((const char*)Xs + (byte ^ ((mrow & 7) << 4)));
    }
#pragma unroll
    for (int rg = 0; rg < 4; rg++)
#pragma unroll
      for (int cg = 0; cg < 4; cg++)
        acc[rg][cg] =
            __builtin_amdgcn_mfma_f32_16x16x32_bf16(af[rg], bk[cg], acc[rg][cg], 0, 0, 0);
  }
  __syncthreads();

#pragma unroll
  for (int cg = 0; cg < 4; cg++) {
    int col = cbase + cg * 16 + lr;
    float bv = biasE[col];
#pragma unroll
    for (int rg = 0; rg < 4; rg++) {
      int r0 = rbase + rg * 16 + lg * 4;
#pragma unroll
      for (int j = 0; j < 4; j++) {
        int row = r0 + j;
        int byte = row * 256 + col * 2;
        *(bf16*)((char*)Xs + (byte ^ ((row & 7) << 4))) =
            __float2bfloat16(lrelu(acc[rg][cg][j] + bv));
      }
    }
  }
  __syncthreads();

  f32x4 acc2[4][4] = {};
#pragma unroll
  for (int ks = 0; ks < 4; ks++) {
    bfv8 bk[4];
#pragma unroll
    for (int cg = 0; cg < 4; cg++)
      bk[cg] = *(const bfv8*)&WbL[(size_t)(cbase + cg * 16 + lr) * 128 + ks * 32 + ko];
    bfv8 af[4];
#pragma unroll
    for (int rg = 0; rg < 4; rg++) {
      int mrow = rbase + rg * 16 + lr;
      int byte = mrow * 256 + (ks * 32 + ko) * 2;
      af[rg] = *(const bfv8*)((const char*)Xs + (byte ^ ((mrow & 7) << 4)));
    }
#pragma unroll
    for (int rg = 0; rg < 4; rg++)
#pragma unroll
      for (int cg = 0; cg < 4; cg++)
        acc2[rg][cg] =
            __builtin_amdgcn_mfma_f32_16x16x32_bf16(af[rg], bk[cg], acc2[rg][cg], 0, 0, 0);
  }

#pragma unroll
  for (int cg = 0; cg < 4; cg++) {
    int col = cbase + cg * 16 + lr;
    float bv = bL[col];
#pragma unroll
    for (int rg = 0; rg < 4; rg++) {
      int r0 = i0 + rbase + rg * 16 + lg * 4;
#pragma unroll
      for (int j = 0; j < 4; j++) {
        int row = r0 + j;
        if (row < M)
          x[(size_t)(row0 + row) * 128 + col] = __float2bfloat16(lrelu(acc2[rg][cg][j] + bv));
      }
    }
  }
}

// Out = lrelu(A @ Wb^T + bias); fallback-path linear
__global__ __launch_bounds__(256) void mfma_lin(const bf16* __restrict__ A,
                                                const bf16* __restrict__ Wb,
                                                const float* __restrict__ bias,
                                                bf16* __restrict__ Out, int M) {
  int t = threadIdx.x;
  int wv = t >> 6, l = t & 63;
  int lr = l & 15, lg = l >> 4;
  int i0 = blockIdx.x * 128;
  int rbase = (wv >> 1) * 64;
  int cbase = (wv & 1) * 64;
  int ko = lg * 8;

  size_t rowoff[4];
#pragma unroll
  for (int rg = 0; rg < 4; rg++) {
    int row = i0 + rbase + rg * 16 + lr;
    if (row > M - 1) row = M - 1;
    rowoff[rg] = (size_t)row * 128;
  }

  bfv8 bfr[4][4];
#pragma unroll
  for (int cg = 0; cg < 4; cg++)
#pragma unroll
    for (int ks = 0; ks < 4; ks++)
      bfr[cg][ks] = *(const bfv8*)&Wb[(size_t)(cbase + cg * 16 + lr) * 128 + ks * 32 + ko];

  f32x4 acc[4][4] = {};
#pragma unroll
  for (int ks = 0; ks < 4; ks++) {
    bfv8 af[4];
#pragma unroll
    for (int rg = 0; rg < 4; rg++) af[rg] = *(const bfv8*)&A[rowoff[rg] + ks * 32 + ko];
#pragma unroll
    for (int rg = 0; rg < 4; rg++)
#pragma unroll
      for (int cg = 0; cg < 4; cg++)
        acc[rg][cg] =
            __builtin_amdgcn_mfma_f32_16x16x32_bf16(af[rg], bfr[cg][ks], acc[rg][cg], 0, 0, 0);
  }

#pragma unroll
  for (int cg = 0; cg < 4; cg++) {
    int col = cbase + cg * 16 + lr;
    float bv = bias[col];
#pragma unroll
    for (int rg = 0; rg < 4; rg++) {
      int row0 = i0 + rbase + rg * 16 + lg * 4;
#pragma unroll
      for (int j = 0; j < 4; j++) {
        int row = row0 + j;
        if (row < M) Out[(size_t)row * 128 + col] = __float2bfloat16(lrelu(acc[rg][cg][j] + bv));
      }
    }
  }
}

// Fused RGCN conv, 32-row blocks (R7 structure): Out = X@root + mean_r0@rw0 + mean_r1@rw1
// + bias. Both rels in one 32KB fp32 LDS tile (vrows 0-31 rel0, 32-63 rel1).
// Gather = ownership items (vrow, 8-col chunk), 4 cursors/thread, ROTATION-FREE BATCHES:
// per batch, 8 edge WORDS -> flat wbuf[8] (LDS-staged elist), then 8 independent
// unbranched X-row loads -> flat v[8], then masked accumulate. No cross-iteration
// register rotation -> compiler cannot collapse the 8-deep load batch (R5-R8's rotating
// v0=v1 pipelines all compiled to VGPR<=52, depth<1, conv pinned at ~160us).
// launch_bounds(256,3): VGPR cap ~168, no spill risk; LDS 40KB still allows 4 blocks/CU.
// TAIL=true fuses lrelu(conv@Wo1^T+bO1)@Wo2^T+bo2 -> out2.
#define ELCAP 2048
template <bool TAIL>
__global__ __launch_bounds__(256, 3) void mfma_conv_f(
    const bf16* __restrict__ X, const int* __restrict__ off, const int* __restrict__ cnt,
    const int* __restrict__ elist, const float* __restrict__ inv,
    const bf16* __restrict__ WB, const float* __restrict__ bias, bf16* __restrict__ Out,
    const bf16* __restrict__ Wo1B, const float* __restrict__ bO1,
    const float* __restrict__ Wo2, const float* __restrict__ bo2,
    float* __restrict__ out2, int M, int NNr, int NEr) {
  __shared__ __align__(16) float At[64 * 128];
  __shared__ int eLs[ELCAP];
  int t = threadIdx.x;
  int wv = t >> 6, l = t & 63;
  int lr = l & 15, lg = l >> 4;
  int i0 = blockIdx.x * 32;
  int cbase = wv * 32;
  int ko = lg * 8;

  int iend = (i0 + 32 < M) ? i0 + 32 : M;
  int e0a = off[i0];
  int n0 = off[iend - 1] + cnt[iend - 1] - e0a;
  int e0b = off[NNr + i0];
  int n1 = off[NNr + iend - 1] + cnt[NNr + iend - 1] - e0b;
  int staged = n0 + n1 < ELCAP ? n0 + n1 : ELCAP;

  // ---- stage elist slices to LDS (coalesced; both rels contiguous CSR ranges) ----
  for (int k = t; k < staged; k += 256)
    eLs[k] = (k < n0) ? elist[e0a + k] : elist[e0b + (k - n0)];

  // cursors: pn=0,1 -> rel0 rows grp, grp+16; pn=2,3 -> rel1 rows grp, grp+16
  int grp = t >> 4;
  int c8 = (t & 15) * 8;
  int stc[4], dgc[4], lbase[4];
#pragma unroll
  for (int pn = 0; pn < 4; pn++) {
    int vr = grp + pn * 16;
    int rel = vr >> 5, m = vr & 31;
    int node = i0 + m;
    bool ok = node < M;
    int idx = rel * NNr + node;
    int so = ok ? off[idx] : 0;
    stc[pn] = so;
    dgc[pn] = ok ? cnt[idx] : 0;
    lbase[pn] = ok ? (rel ? n0 + (so - e0b) : so - e0a) : 0;
  }
  __syncthreads();

  // ---- rotation-free batched gather: 8 words -> 8 loads -> masked accumulate ----
  float s[4][8] = {};
  {
    int dmax = max(max(dgc[0], dgc[1]), max(dgc[2], dgc[3]));

    auto eword = [&](int pn, int e) -> unsigned {
      int ec = e < dgc[pn] - 1 ? e : dgc[pn] - 1;  // clamp within list
      ec = ec < 0 ? 0 : ec;
      int li = lbase[pn] + ec;
      if (li < staged) return (unsigned)eLs[li];
      int g = stc[pn] + ec;
      g = g < NEr - 1 ? g : NEr - 1;
      return (unsigned)elist[g];
    };

    for (int e0 = 0; e0 < dmax; e0 += 2) {
      unsigned wbuf[8];
#pragma unroll
      for (int pn = 0; pn < 4; pn++) {
        wbuf[2 * pn] = eword(pn, e0);
        wbuf[2 * pn + 1] = eword(pn, e0 + 1);
      }
      bfv8 v[8];
#pragma unroll
      for (int q = 0; q < 8; q++)
        v[q] = *(const bfv8*)&X[(size_t)(wbuf[q] & 0xFFFFFF) * 128 + c8];
#pragma unroll
      for (int pn = 0; pn < 4; pn++) {
        float m0 = e0 < dgc[pn] ? 1.f : 0.f;
        float m1 = e0 + 1 < dgc[pn] ? 1.f : 0.f;
#pragma unroll
        for (int j = 0; j < 8; j++)
          s[pn][j] +=
              m0 * __bfloat162float(v[2 * pn][j]) + m1 * __bfloat162float(v[2 * pn + 1][j]);
      }
    }
  }
#pragma unroll
  for (int pn = 0; pn < 4; pn++) {
    int vr = grp + pn * 16;
    int sw = (vr & 7) << 4;
    int lb = vr * 512 + c8 * 4;
    *(float4*)((char*)At + (lb ^ sw)) = make_float4(s[pn][0], s[pn][1], s[pn][2], s[pn][3]);
    *(float4*)((char*)At + ((lb + 16) ^ sw)) =
        make_float4(s[pn][4], s[pn][5], s[pn][6], s[pn][7]);
  }

  // row clamps and inv scales
  size_t rowoff[2];
  float iv0[2], iv1[2];
#pragma unroll
  for (int rg = 0; rg < 2; rg++) {
    int row = i0 + rg * 16 + lr;
    int rc = row < M ? row : M - 1;
    rowoff[rg] = (size_t)rc * 128;
    iv0[rg] = row < M ? inv[row] : 0.f;
    iv1[rg] = row < M ? inv[NNr + row] : 0.f;
  }

  f32x4 acc[2][2] = {};

  // ---- seg 0: X @ root from global (overlaps gather LDS-store latency) ----
#pragma unroll
  for (int ks = 0; ks < 4; ks++) {
    bfv8 bk[2];
#pragma unroll
    for (int cg = 0; cg < 2; cg++)
      bk[cg] = *(const bfv8*)&WB[(size_t)(cbase + cg * 16 + lr) * 128 + ks * 32 + ko];
    bfv8 af[2];
#pragma unroll
    for (int rg = 0; rg < 2; rg++) af[rg] = *(const bfv8*)&X[rowoff[rg] + ks * 32 + ko];
#pragma unroll
    for (int rg = 0; rg < 2; rg++)
#pragma unroll
      for (int cg = 0; cg < 2; cg++)
        acc[rg][cg] =
            __builtin_amdgcn_mfma_f32_16x16x32_bf16(af[rg], bk[cg], acc[rg][cg], 0, 0, 0);
  }
  __syncthreads();

  // ---- rel-0 / rel-1 MFMA from LDS (inv-scaled, cvt to bf16) ----
#pragma unroll
  for (int r = 0; r < 2; r++) {
    const bf16* Wb = WB + 16384 * (1 + r);
#pragma unroll
    for (int ks = 0; ks < 4; ks++) {
      bfv8 bk[2];
#pragma unroll
      for (int cg = 0; cg < 2; cg++)
        bk[cg] = *(const bfv8*)&Wb[(size_t)(cbase + cg * 16 + lr) * 128 + ks * 32 + ko];
      bfv8 af[2];
#pragma unroll
      for (int rg = 0; rg < 2; rg++) {
        int mrow = r * 32 + rg * 16 + lr;
        int lb = mrow * 512 + ks * 128 + ko * 4;
        int sw = (mrow & 7) << 4;
        float4 f0 = *(const float4*)((const char*)At + (lb ^ sw));
        float4 f1 = *(const float4*)((const char*)At + ((lb + 16) ^ sw));
        float iv = r ? iv1[rg] : iv0[rg];
        bfv8 a;
        a[0] = (__bf16)(f0.x * iv); a[1] = (__bf16)(f0.y * iv);
        a[2] = (__bf16)(f0.z * iv); a[3] = (__bf16)(f0.w * iv);
        a[4] = (__bf16)(f1.x * iv); a[5] = (__bf16)(f1.y * iv);
        a[6] = (__bf16)(f1.z * iv); a[7] = (__bf16)(f1.w * iv);
        af[rg] = a;
      }
#pragma unroll
      for (int rg = 0; rg < 2; rg++)
#pragma unroll
        for (int cg = 0; cg < 2; cg++)
          acc[rg][cg] =
              __builtin_amdgcn_mfma_f32_16x16x32_bf16(af[rg], bk[cg], acc[rg][cg], 0, 0, 0);
    }
  }

  if (!TAIL) {
#pragma unroll
    for (int cg = 0; cg < 2; cg++) {
      int col = cbase + cg * 16 + lr;
      float bv = bias[col];
#pragma unroll
      for (int rg = 0; rg < 2; rg++) {
        int row0 = i0 + rg * 16 + lg * 4;
#pragma unroll
        for (int j = 0; j < 4; j++) {
          int row = row0 + j;
          if (row < M) Out[(size_t)row * 128 + col] = __float2bfloat16(acc[rg][cg][j] + bv);
        }
      }
    }
  } else {
    // ---- fused tail: y = conv_out + bias (bf16, LDS, swizzled) ----
    __syncthreads();  // all At reads done before overwrite
#pragma unroll
    for (int cg = 0; cg < 2; cg++) {
      int col = cbase + cg * 16 + lr;
      float bv = bias[col];
#pragma unroll
      for (int rg = 0; rg < 2; rg++) {
#pragma unroll
        for (int j = 0; j < 4; j++) {
          int row32 = rg * 16 + lg * 4 + j;
          int byte = row32 * 256 + col * 2;
          *(bf16*)((char*)At + (byte ^ ((row32 & 7) << 4))) =
              __float2bfloat16(acc[rg][cg][j] + bv);
        }
      }
    }
    __syncthreads();

    // z = lrelu(y @ Wo1^T + bO1): 32 rows x 128 cols
    f32x4 acc2[2][2] = {};
#pragma unroll
    for (int ks = 0; ks < 4; ks++) {
      bfv8 bk[2];
#pragma unroll
      for (int cg = 0; cg < 2; cg++)
        bk[cg] = *(const bfv8*)&Wo1B[(size_t)(cbase + cg * 16 + lr) * 128 + ks * 32 + ko];
      bfv8 af[2];
#pragma unroll
      for (int rg = 0; rg < 2; rg++) {
        int mrow = rg * 16 + lr;
        int byte = mrow * 256 + (ks * 32 + ko) * 2;
        af[rg] = *(const bfv8*)((const char*)At + (byte ^ ((mrow & 7) << 4)));
      }
#pragma unroll
      for (int rg = 0; rg < 2; rg++)
#pragma unroll
        for (int cg = 0; cg < 2; cg++)
          acc2[rg][cg] =
              __builtin_amdgcn_mfma_f32_16x16x32_bf16(af[rg], bk[cg], acc2[rg][cg], 0, 0, 0);
    }
    // store z (bf16, LDS bytes [8192,16384), no swizzle)
#pragma unroll
    for (int cg = 0; cg < 2; cg++) {
      int col = cbase + cg * 16 + lr;
      float bv = bO1[col];
#pragma unroll
      for (int rg = 0; rg < 2; rg++) {
#pragma unroll
        for (int j = 0; j < 4; j++) {
          int row32 = rg * 16 + lg * 4 + j;
          *(bf16*)((char*)At + 8192 + row32 * 256 + col * 2) =
              __float2bfloat16(lrelu(acc2[rg][cg][j] + bv));
        }
      }
    }
    __syncthreads();

    // out2[row] = z_row @ Wo2^T + bo2; 8 threads per row, shuffle-reduce
    int row = t >> 3, seg = t & 7;
    const bf16* zr = (const bf16*)((const char*)At + 8192 + row * 256 + seg * 32);
    float p0 = 0.f, p1 = 0.f;
#pragma unroll
    for (int q = 0; q < 16; q++) {
      float xv = __bfloat162float(zr[q]);
      int col = seg * 16 + q;
      p0 += xv * Wo2[col];
      p1 += xv * Wo2[128 + col];
    }
#pragma unroll
    for (int o = 4; o; o >>= 1) {
      p0 += __shfl_down(p0, o, 8);
      p1 += __shfl_down(p1, o, 8);
    }
    int grow = i0 + row;
    if (seg == 0 && grow < M) {
      out2[(size_t)grow * 2] = p0 + bo2[0];
      out2[(size_t)grow * 2 + 1] = p1 + bo2[1];
    }
  }
}

// ---------------- pipeline (bf16 storage, MFMA everywhere, fused ends) ----------------
static void run_pipeline(void* const* d_in, const int* S, float* out, char* ws,
                         int NUr, int NTr, int NEr, int dDes, int dNum, int dCat, int dTw,
                         hipStream_t stream) {
  const int NNr = NUr + NTr;
  const size_t xbytes = (size_t)NNr * 128 * 2;

  bf16* xa = (bf16*)ws;
  bf16* xb = (bf16*)(ws + xbytes);
  char* p = ws + 2 * xbytes;
  int* cnt = (int*)p;      p += (size_t)2 * NNr * 4;
  int* fill = (int*)p;     p += (size_t)2 * NNr * 4;  // contiguous with cnt
  int* off = (int*)p;      p += (size_t)2 * NNr * 4;
  int* bsum = (int*)p;     p += 2048 * 4;             // contiguous with bsumsc
  int* bsumsc = (int*)p;   p += 2048 * 4;
  float* inv = (float*)p;  p += (size_t)2 * NNr * 4;
  int* elist = (int*)p;    p += (size_t)NEr * 4;
  float* pw = (float*)p;   p += (size_t)PW_TOTAL * 4;
  int* flags = (int*)p;

  // ---- format probes: one launch ----
  ProbeArgs pa;
  for (int i = 0; i < 23; i++) {
    int src = (i == 22) ? 21 : i;  // b_o2 (2 elems) inherits W_o2's dtype
    pa.p[i] = d_in[src];
    if (i == 4) {
      pa.mode[i] = 1;
      pa.s[i] = NEr < 256 ? NEr : 256;
    } else if (i == 5) {
      pa.mode[i] = 1;
      int s2 = NEr / 2 < 256 ? NEr / 2 : 256;
      pa.s[i] = s2 < 1 ? 1 : s2;
    } else {
      pa.mode[i] = 0;
      int s = S[src] / 2;
      if (s > 256) s = 256;
      if (s < 1) s = 1;
      pa.s[i] = s;
    }
  }
  detect_all<<<23, 256, 0, stream>>>(pa, flags);
  prep_weights<<<(PW_W_TOTAL + 255) / 256, 256, 0, stream>>>(
      d_in[14], d_in[15], d_in[16], d_in[17], d_in[18], d_in[19], d_in[20], d_in[21],
      d_in[22], flags, pw);
  prep_enc<<<129, 256, 0, stream>>>(d_in[6], d_in[7], d_in[8], d_in[9], d_in[10], d_in[11],
                                    d_in[12], d_in[13], flags, dDes, dNum, dCat, dTw, pw);

  const float* bIn = pw + 81920;
  const float* rbp = pw + 82048;
  const float* bO1 = pw + 82176;
  const float* Wo2p = pw + 82304;
  const float* bo2p = pw + 82560;
  const bf16* WinB = (const bf16*)(pw + BF_BASE);
  const bf16* Wo1B = (const bf16*)(pw + BF_BASE + 8192);
  const bf16* ConvB = (const bf16*)(pw + BF_BASE + 16384);  // rootB, rwB0, rwB1
  const bf16* EncU = (const bf16*)(pw + ENC_BASE);
  const bf16* EncT = (const bf16*)(pw + ENC_BASE + 8192);
  const float* bU = pw + ENC_BASE + 16384;
  const float* bT = bU + 128;

  const void* ei = d_in[4];
  const void* et = d_in[5];
  const int nb1 = (2 * NNr + 1023) / 1024;

  // ---- CSR build ----
  zero_ints<<<(4 * NNr + 255) / 256, 256, 0, stream>>>(cnt, 4 * NNr);
  zero_ints<<<16, 256, 0, stream>>>(bsum, 4096);
  count_edges<<<(NEr + 255) / 256, 256, 0, stream>>>(ei, et, flags, cnt, NEr, NNr);
  scan_blocks<<<nb1, 256, 0, stream>>>(cnt, off, bsum, 2 * NNr);
  scan_blocks<<<1, 256, 0, stream>>>(bsum, bsumsc, nullptr, nb1);
  scan_add_inv<<<(2 * NNr + 255) / 256, 256, 0, stream>>>(off, bsumsc, cnt, inv, 2 * NNr);
  fill_elist<<<(NEr + 255) / 256, 256, 0, stream>>>(ei, et, flags, off, fill, elist, NEr, NNr);

  // ---- encoders (fused with W_in) -> xb ----
  if (dDes + dNum + dCat <= 128 && dTw <= 128) {
    enc_mfma<<<(NUr + 127) / 128, 256, 0, stream>>>(d_in[0], d_in[2], d_in[3], flags, 0, 2, 3,
                                                    dDes, dNum, dCat, EncU, bU, WinB, bIn, xb,
                                                    NUr, 0);
    enc_mfma<<<(NTr + 127) / 128, 256, 0, stream>>>(d_in[1], nullptr, nullptr, flags, 1, 1, 1,
                                                    dTw, 0, 0, EncT, bT, WinB, bIn, xb, NTr,
                                                    NUr);
  } else {
    enc_gemm<<<(NUr + 63) / 64, 256, 0, stream>>>(d_in[0], d_in[6], d_in[7], flags, 0, 6, 7,
                                                  xa, NUr, dDes, 64, 0, 0);
    enc_gemm<<<(NUr + 63) / 64, 256, 0, stream>>>(d_in[2], d_in[8], d_in[9], flags, 2, 8, 9,
                                                  xa, NUr, dNum, 32, 0, 64);
    enc_gemm<<<(NUr + 63) / 64, 256, 0, stream>>>(d_in[3], d_in[10], d_in[11], flags, 3, 10,
                                                  11, xa, NUr, dCat, 32, 0, 96);
    enc_gemm<<<(NTr + 63) / 64, 256, 0, stream>>>(d_in[1], d_in[12], d_in[13], flags, 1, 12,
                                                  13, xa, NTr, dTw, 128, NUr, 0);
    mfma_lin<<<(NNr + 127) / 128, 256, 0, stream>>>(xa, WinB, bIn, xb, NNr);
  }

  const int mt32 = (NNr + 31) / 32;
  mfma_conv_f<false><<<mt32, 256, 0, stream>>>(xb, off, cnt, elist, inv, ConvB, rbp, xa,
                                               nullptr, nullptr, nullptr, nullptr, nullptr,
                                               NNr, NNr, NEr);
  mfma_conv_f<true><<<mt32, 256, 0, stream>>>(xa, off, cnt, elist, inv, ConvB, rbp, nullptr,
                                              Wo1B, bO1, Wo2p, bo2p, out, NNr, NNr, NEr);
}

extern "C" void kernel_launch(void* const* d_in, const int* in_sizes, int n_in,
                              void* d_out, int out_size, void* d_ws, size_t ws_size,
                              hipStream_t stream) {
  float* out = (float*)d_out;
  char* ws = (char*)d_ws;

  auto signal = [&](int k) {
    sig_fill<<<(out_size + 255) / 256, 256, 0, stream>>>(out, out_size, (float)(200 + k));
  };

  if (n_in != 23) { signal(1); return; }
  const int* S = in_sizes;
  if (S[7] != 64 || S[9] != 32 || S[11] != 32 || S[13] != 128) { signal(2); return; }
  if (S[15] != 128) { signal(3); return; }
  if (S[6] % 64 || S[8] % 32 || S[10] % 32 || S[12] % 128) { signal(4); return; }
  int dDes = S[6] / 64, dNum = S[8] / 32, dCat = S[10] / 32, dTw = S[12] / 128;
  if (dDes <= 0 || dTw <= 0 || S[0] % dDes || S[1] % dTw) { signal(5); return; }
  if (dDes > 101 || dNum > 101 || dCat > 101 || dTw > 101) { signal(4); return; }
  int NUr = S[0] / dDes, NTr = S[1] / dTw, NNr = NUr + NTr, NEr = S[5];
  if (S[2] != NUr * dNum || S[3] != NUr * dCat) { signal(5); return; }
  if (S[4] != 2 * NEr || NEr < 1024) { signal(6); return; }
  if (NNr >= (1 << 24)) { signal(6); return; }  // elist src-packing limit
  if (S[14] != 16384 || S[16] != 32768 || S[17] != 16384 || S[18] != 128 ||
      S[19] != 16384 || S[20] != 128 || S[21] != 256 || S[22] != 2) { signal(7); return; }
  if (out_size != NNr * 2) { signal(8); return; }

  const size_t smallBytes = (size_t)4 * ((size_t)2 * NNr * 4) + 2 * 2048 * 4 +
                            (size_t)NEr * 4 + (size_t)PW_TOTAL * 4 + 512;
  const size_t need = 2 * (size_t)NNr * 128 * 2 + smallBytes;

  if (ws_size >= need) {
    run_pipeline(d_in, S, out, ws, NUr, NTr, NEr, dDes, dNum, dCat, dTw, stream);
  } else {
    signal(9);
  }
}

// Round 10
// 518.161 us; speedup vs baseline: 1.2506x; 1.0429x over previous
//
#include <hip/hip_runtime.h>
#include <hip/hip_bf16.h>

typedef __hip_bfloat16 bf16;

typedef __bf16 bfv8 __attribute__((ext_vector_type(8)));
typedef float f32x4 __attribute__((ext_vector_type(4)));

__device__ __forceinline__ float lrelu(float x) { return x > 0.f ? x : 0.01f * x; }

__device__ __forceinline__ float ldv(float v) { return v; }
__device__ __forceinline__ float ldv(bf16 v) { return __bfloat162float(v); }
__device__ __forceinline__ void stv(float* p, float v) { *p = v; }
__device__ __forceinline__ void stv(bf16* p, float v) { *p = __float2bfloat16(v); }

__device__ __forceinline__ float in_rd(const void* p, size_t i, int isbf) {
  return isbf ? __bfloat162float(((const bf16*)p)[i]) : ((const float*)p)[i];
}
__device__ __forceinline__ int ix_rd(const void* p, size_t i, int is64) {
  return is64 ? (int)((const long long*)p)[i] : ((const int*)p)[i];
}

// ---------------- fused per-array format probe: one launch, 23 blocks ----------------
struct ProbeArgs {
  const void* p[23];
  int s[23];
  int mode[23];
};

__global__ void detect_all(ProbeArgs a, int* __restrict__ flags) {
  __shared__ int sh[256];
  int b = blockIdx.x;
  const unsigned int* w = (const unsigned int*)a.p[b];
  int s = a.s[b], mode = a.mode[b];
  int t = threadIdx.x;
  int c = 0;
  if (t < s) {
    if (mode == 0) {
      unsigned int v = w[t];
      int e = (v >> 7) & 0xFF;
      c = (e >= 100 && e <= 140) ? 1 : 0;
    } else {
      c = (w[2 * t + 1] == 0u) ? 1 : 0;
    }
  }
  sh[t] = c;
  __syncthreads();
  for (int d = 128; d; d >>= 1) {
    if (t < d) sh[t] += sh[t + d];
    __syncthreads();
  }
  if (t == 0) flags[b] = (mode == 0) ? (sh[0] * 10 >= 7 * s) : (sh[0] * 10 >= 9 * s);
}

// ---------------- weight prep ----------------
// fp32 region (floats): [0,16384) W_inT [k,n]; [16384,32768) W_o1T [k,n]; [32768,49152) root;
// [49152,81920) rw; [81920] b_in; [82048] rgcn_bias; [82176] b_o1; [82304] W_o2; [82560] b_o2
// bf16 region (float index BF_BASE): 5x [128][128] bf16 [out][in]:
//   m=0 WinB; m=1 Wo1B; m=2 rootB; m=3 rwB0; m=4 rwB1
// ENC region (float index ENC_BASE): EncU bf16[128][128]; EncT bf16[128][128]; biasU; biasT
#define PW_F32 82562
#define BF_BASE 82564
#define PW_W_TOTAL (BF_BASE + 5 * 8192)
#define ENC_BASE PW_W_TOTAL
#define PW_TOTAL (ENC_BASE + 16384 + 256)
__global__ void prep_weights(const void* Win, const void* bin, const void* rw,
                             const void* root, const void* rb, const void* Wo1,
                             const void* bo1, const void* Wo2, const void* bo2,
                             const int* __restrict__ fl, float* __restrict__ pw) {
  int i = blockIdx.x * 256 + threadIdx.x;
  if (i >= PW_W_TOTAL) return;
  if (i < 16384) {
    int k = i >> 7, o = i & 127;
    pw[i] = in_rd(Win, (size_t)o * 128 + k, fl[14]);
  } else if (i < 32768) {
    int j = i - 16384;
    int k = j >> 7, o = j & 127;
    pw[i] = in_rd(Wo1, (size_t)o * 128 + k, fl[19]);
  } else if (i < 49152) {
    pw[i] = in_rd(root, i - 32768, fl[17]);
  } else if (i < 81920) {
    pw[i] = in_rd(rw, i - 49152, fl[16]);
  } else if (i < 82048) {
    pw[i] = in_rd(bin, i - 81920, fl[15]);
  } else if (i < 82176) {
    pw[i] = in_rd(rb, i - 82048, fl[18]);
  } else if (i < 82304) {
    pw[i] = in_rd(bo1, i - 82176, fl[20]);
  } else if (i < 82560) {
    pw[i] = in_rd(Wo2, i - 82304, fl[21]);
  } else if (i < PW_F32) {
    pw[i] = in_rd(bo2, i - 82560, fl[22]);
  } else if (i >= BF_BASE) {
    int j = i - BF_BASE;
    bf16* bw = (bf16*)(pw + BF_BASE);
#pragma unroll
    for (int q = 0; q < 2; q++) {
      int u = 2 * j + q;
      int m = u >> 14, r = u & 16383;
      int n = r >> 7, k = r & 127;
      float v;
      if (m == 0) v = in_rd(Win, (size_t)n * 128 + k, fl[14]);
      else if (m == 1) v = in_rd(Wo1, (size_t)n * 128 + k, fl[19]);
      else if (m == 2) v = in_rd(root, (size_t)k * 128 + n, fl[17]);
      else v = in_rd(rw, (size_t)(m - 3) * 16384 + (size_t)k * 128 + n, fl[16]);
      bw[u] = __float2bfloat16(v);
    }
  }
}

// Builds fused encoder weights/biases.
__global__ void prep_enc(const void* Wd, const void* bd, const void* Wn, const void* bn,
                         const void* Wc, const void* bc, const void* Wt, const void* bt,
                         const int* __restrict__ fl, int dDes, int dNum, int dCat, int dTw,
                         float* __restrict__ pw) {
  int i = blockIdx.x * 256 + threadIdx.x;
  bf16* e = (bf16*)(pw + ENC_BASE);
  float* bU = pw + ENC_BASE + 16384;
  float* bT = bU + 128;
  if (i < 16384) {
    int n = i >> 7, k = i & 127;
    float v = 0.f;
    if (n < 64) {
      if (k < dDes) v = in_rd(Wd, (size_t)n * dDes + k, fl[6]);
    } else if (n < 96) {
      int kk = k - dDes;
      if (kk >= 0 && kk < dNum) v = in_rd(Wn, (size_t)(n - 64) * dNum + kk, fl[8]);
    } else {
      int kk = k - dDes - dNum;
      if (kk >= 0 && kk < dCat) v = in_rd(Wc, (size_t)(n - 96) * dCat + kk, fl[10]);
    }
    e[i] = __float2bfloat16(v);
  } else if (i < 32768) {
    int j = i - 16384;
    int n = j >> 7, k = j & 127;
    float v = (k < dTw) ? in_rd(Wt, (size_t)n * dTw + k, fl[12]) : 0.f;
    e[i] = __float2bfloat16(v);
  } else if (i < 32896) {
    int j = i - 32768;
    bU[j] = (j < 64) ? in_rd(bd, j, fl[7])
                     : (j < 96) ? in_rd(bn, j - 64, fl[9]) : in_rd(bc, j - 96, fl[11]);
  } else if (i < 33024) {
    bT[i - 32896] = in_rd(bt, i - 32896, fl[13]);
  }
}

// ---------------- utilities ----------------
__global__ void sig_fill(float* __restrict__ p, int n, float v) {
  int i = blockIdx.x * 256 + threadIdx.x;
  if (i < n) p[i] = v;
}
__global__ void zero_ints(int* __restrict__ p, int n) {
  int i = blockIdx.x * 256 + threadIdx.x;
  if (i < n) p[i] = 0;
}

// ---------------- CSR build ----------------
__global__ void count_edges(const void* __restrict__ ei, const void* __restrict__ et,
                            const int* __restrict__ fl, int* __restrict__ cnt, int NEr,
                            int NNr) {
  int e = blockIdx.x * 256 + threadIdx.x;
  if (e >= NEr) return;
  int d = ix_rd(ei, (size_t)NEr + e, fl[4]);
  int r = ix_rd(et, e, fl[5]) & 1;
  if ((unsigned)d >= (unsigned)NNr) return;
  atomicAdd(&cnt[r * NNr + d], 1);
}

__global__ void scan_blocks(const int* __restrict__ in, int* __restrict__ out,
                            int* __restrict__ bsum, int n) {
  __shared__ int sh[256];
  int t = threadIdx.x;
  int base = blockIdx.x * 1024 + t * 4;
  int a[4];
  int s = 0;
#pragma unroll
  for (int i = 0; i < 4; i++) {
    a[i] = (base + i < n) ? in[base + i] : 0;
    s += a[i];
  }
  sh[t] = s;
  __syncthreads();
  for (int d = 1; d < 256; d <<= 1) {
    int v = (t >= d) ? sh[t - d] : 0;
    __syncthreads();
    sh[t] += v;
    __syncthreads();
  }
  int ex = sh[t] - s;
#pragma unroll
  for (int i = 0; i < 4; i++) {
    if (base + i < n) out[base + i] = ex;
    ex += a[i];
  }
  if (t == 255 && bsum) bsum[blockIdx.x] = sh[255];
}

__global__ void scan_add_inv(int* __restrict__ off, const int* __restrict__ bsumsc,
                             const int* __restrict__ cnt, float* __restrict__ inv, int n) {
  int i = blockIdx.x * 256 + threadIdx.x;
  if (i >= n) return;
  off[i] += bsumsc[i >> 10];
  inv[i] = 1.f / fmaxf((float)cnt[i], 1.f);
}

// elist word packs: bits [0,24) = src node id
__global__ void fill_elist(const void* __restrict__ ei, const void* __restrict__ et,
                           const int* __restrict__ fl, const int* __restrict__ off,
                           int* __restrict__ fill, int* __restrict__ elist, int NEr, int NNr) {
  int e = blockIdx.x * 256 + threadIdx.x;
  if (e >= NEr) return;
  int s = ix_rd(ei, e, fl[4]);
  int d = ix_rd(ei, (size_t)NEr + e, fl[4]);
  int r = ix_rd(et, e, fl[5]) & 1;
  if ((unsigned)d >= (unsigned)NNr || (unsigned)s >= (unsigned)NNr) return;
  int idx = r * NNr + d;
  int slot = off[idx] + atomicAdd(&fill[idx], 1);
  elist[slot] = s | ((d & 127) << 24);
}

// ---------------- legacy encoder GEMM (fallback for oversized K) ----------------
__global__ __launch_bounds__(256) void enc_gemm(const void* __restrict__ A,
                                                const void* __restrict__ W,
                                                const void* __restrict__ B,
                                                const int* __restrict__ fl, int fa, int fw,
                                                int fb, bf16* __restrict__ x, int M, int K,
                                                int N, int row0, int col0) {
  __shared__ float Wb[128 * 102];
  __shared__ float bb[128];
  int t = threadIdx.x;
  int stride = (K & 1) ? K : K + 1;
  int fA = fl[fa];
  {
    int fW = fl[fw], fB = fl[fb];
    for (int idx = t; idx < N * K; idx += 256) {
      int j = idx / K, k = idx - j * K;
      Wb[j * stride + k] = in_rd(W, (size_t)j * K + k, fW);
    }
    if (t < N) bb[t] = in_rd(B, t, fB);
  }
  __syncthreads();
  int j = t % N;
  int r = t / N;
  int R = 256 / N;
  int iEnd = blockIdx.x * 64 + 64;
  if (iEnd > M) iEnd = M;
  const float* wrow = &Wb[j * stride];
  if (!fA) {
    const float* Af = (const float*)A;
    for (int i = blockIdx.x * 64 + r; i < iEnd; i += R) {
      const float* a = Af + (size_t)i * K;
      float acc = bb[j];
      for (int k = 0; k < K; k++) acc += a[k] * wrow[k];
      stv(&x[(size_t)(row0 + i) * 128 + col0 + j], lrelu(acc));
    }
  } else {
    const bf16* Ab = (const bf16*)A;
    for (int i = blockIdx.x * 64 + r; i < iEnd; i += R) {
      const bf16* a = Ab + (size_t)i * K;
      float acc = bb[j];
      for (int k = 0; k < K; k++) acc += __bfloat162float(a[k]) * wrow[k];
      stv(&x[(size_t)(row0 + i) * 128 + col0 + j], lrelu(acc));
    }
  }
}

// ================= MFMA GEMMs (bf16 storage, fp32 accumulate) =================
// v_mfma_f32_16x16x32_bf16 fragments (m89/m91-verified C/D mapping):
//   A: lane l holds A[m = l&15][k = (l>>4)*8 + i]
//   B: lane l holds B[k = (l>>4)*8 + i][n = l&15]  (= Wt[n][k], Wt in [out][in] layout)
//   D: lane l reg j -> row = (l>>4)*4 + j, col = l&15

// Fused MFMA encoder: input segs -> LDS bf16 tile -> enc MFMA + lrelu -> LDS ->
// W_in MFMA + lrelu -> global. LDS rows XOR-swizzled (byte ^= (row&7)<<4).
__global__ __launch_bounds__(256) void enc_mfma(
    const void* __restrict__ A0, const void* __restrict__ A1, const void* __restrict__ A2,
    const int* __restrict__ fl, int fi0, int fi1, int fi2, int K0, int K1, int K2,
    const bf16* __restrict__ WbE, const float* __restrict__ biasE,
    const bf16* __restrict__ WbL, const float* __restrict__ bL, bf16* __restrict__ x,
    int M, int row0) {
  __shared__ __align__(16) bf16 Xs[16384];
  int t = threadIdx.x;
  int i0 = blockIdx.x * 128;

  {
    uint4 z = {0u, 0u, 0u, 0u};
#pragma unroll
    for (int i = 0; i < 8; i++) *(uint4*)((char*)Xs + i * 4096 + t * 16) = z;
  }
  __syncthreads();

  const void* As[3] = {A0, A1, A2};
  int Ks_[3] = {K0, K1, K2};
  int fis[3] = {fi0, fi1, fi2};
  int cb = 0;
  for (int s = 0; s < 3; s++) {
    int Ks = Ks_[s];
    if (Ks <= 0) continue;
    int isbf = fl[fis[s]];
    const void* A = As[s];
    int total = 128 * Ks;
    for (int f = t; f < total; f += 256) {
      int row = f / Ks;
      int k = f - row * Ks;
      int gr = i0 + row;
      float v = (gr < M) ? in_rd(A, (size_t)gr * Ks + k, isbf) : 0.f;
      int byte = row * 256 + (cb + k) * 2;
      *(bf16*)((char*)Xs + (byte ^ ((row & 7) << 4))) = __float2bfloat16(v);
    }
    cb += Ks;
  }
  __syncthreads();

  int wv = t >> 6, l = t & 63;
  int lr = l & 15, lg = l >> 4;
  int rbase = (wv >> 1) * 64, cbase = (wv & 1) * 64;
  int ko = lg * 8;
  f32x4 acc[4][4] = {};
#pragma unroll
  for (int ks = 0; ks < 4; ks++) {
    bfv8 bk[4];
#pragma unroll
    for (int cg = 0; cg < 4; cg++)
      bk[cg] = *(const bfv8*)&WbE[(size_t)(cbase + cg * 16 + lr) * 128 + ks * 32 + ko];
    bfv8 af[4];
#pragma unroll
    for (int rg = 0; rg < 4; rg++) {
      int mrow = rbase + rg * 16 + lr;
      int byte = mrow * 256 + (ks * 32 + ko) * 2;
      af[rg] = *(const bfv8*)((const char*)Xs + (byte ^ ((mrow & 7) << 4)));
    }
#pragma unroll
    for (int rg = 0; rg < 4; rg++)
#pragma unroll
      for (int cg = 0; cg < 4; cg++)
        acc[rg][cg] =
            __builtin_amdgcn_mfma_f32_16x16x32_bf16(af[rg], bk[cg], acc[rg][cg], 0, 0, 0);
  }
  __syncthreads();

#pragma unroll
  for (int cg = 0; cg < 4; cg++) {
    int col = cbase + cg * 16 + lr;
    float bv = biasE[col];
#pragma unroll
    for (int rg = 0; rg < 4; rg++) {
      int r0 = rbase + rg * 16 + lg * 4;
#pragma unroll
      for (int j = 0; j < 4; j++) {
        int row = r0 + j;
        int byte = row * 256 + col * 2;
        *(bf16*)((char*)Xs + (byte ^ ((row & 7) << 4))) =
            __float2bfloat16(lrelu(acc[rg][cg][j] + bv));
      }
    }
  }
  __syncthreads();

  f32x4 acc2[4][4] = {};
#pragma unroll
  for (int ks = 0; ks < 4; ks++) {
    bfv8 bk[4];
#pragma unroll
    for (int cg = 0; cg < 4; cg++)
      bk[cg] = *(const bfv8*)&WbL[(size_t)(cbase + cg * 16 + lr) * 128 + ks * 32 + ko];
    bfv8 af[4];
#pragma unroll
    for (int rg = 0; rg < 4; rg++) {
      int mrow = rbase + rg * 16 + lr;
      int byte = mrow * 256 + (ks * 32 + ko) * 2;
      af[rg] = *(const bfv8*)((const char*)Xs + (byte ^ ((mrow & 7) << 4)));
    }
#pragma unroll
    for (int rg = 0; rg < 4; rg++)
#pragma unroll
      for (int cg = 0; cg < 4; cg++)
        acc2[rg][cg] =
            __builtin_amdgcn_mfma_f32_16x16x32_bf16(af[rg], bk[cg], acc2[rg][cg], 0, 0, 0);
  }

#pragma unroll
  for (int cg = 0; cg < 4; cg++) {
    int col = cbase + cg * 16 + lr;
    float bv = bL[col];
#pragma unroll
    for (int rg = 0; rg < 4; rg++) {
      int r0 = i0 + rbase + rg * 16 + lg * 4;
#pragma unroll
      for (int j = 0; j < 4; j++) {
        int row = r0 + j;
        if (row < M)
          x[(size_t)(row0 + row) * 128 + col] = __float2bfloat16(lrelu(acc2[rg][cg][j] + bv));
      }
    }
  }
}

// Out = lrelu(A @ Wb^T + bias); fallback-path linear
__global__ __launch_bounds__(256) void mfma_lin(const bf16* __restrict__ A,
                                                const bf16* __restrict__ Wb,
                                                const float* __restrict__ bias,
                                                bf16* __restrict__ Out, int M) {
  int t = threadIdx.x;
  int wv = t >> 6, l = t & 63;
  int lr = l & 15, lg = l >> 4;
  int i0 = blockIdx.x * 128;
  int rbase = (wv >> 1) * 64;
  int cbase = (wv & 1) * 64;
  int ko = lg * 8;

  size_t rowoff[4];
#pragma unroll
  for (int rg = 0; rg < 4; rg++) {
    int row = i0 + rbase + rg * 16 + lr;
    if (row > M - 1) row = M - 1;
    rowoff[rg] = (size_t)row * 128;
  }

  bfv8 bfr[4][4];
#pragma unroll
  for (int cg = 0; cg < 4; cg++)
#pragma unroll
    for (int ks = 0; ks < 4; ks++)
      bfr[cg][ks] = *(const bfv8*)&Wb[(size_t)(cbase + cg * 16 + lr) * 128 + ks * 32 + ko];

  f32x4 acc[4][4] = {};
#pragma unroll
  for (int ks = 0; ks < 4; ks++) {
    bfv8 af[4];
#pragma unroll
    for (int rg = 0; rg < 4; rg++) af[rg] = *(const bfv8*)&A[rowoff[rg] + ks * 32 + ko];
#pragma unroll
    for (int rg = 0; rg < 4; rg++)
#pragma unroll
      for (int cg = 0; cg < 4; cg++)
        acc[rg][cg] =
            __builtin_amdgcn_mfma_f32_16x16x32_bf16(af[rg], bfr[cg][ks], acc[rg][cg], 0, 0, 0);
  }

#pragma unroll
  for (int cg = 0; cg < 4; cg++) {
    int col = cbase + cg * 16 + lr;
    float bv = bias[col];
#pragma unroll
    for (int rg = 0; rg < 4; rg++) {
      int row0 = i0 + rbase + rg * 16 + lg * 4;
#pragma unroll
      for (int j = 0; j < 4; j++) {
        int row = row0 + j;
        if (row < M) Out[(size_t)row * 128 + col] = __float2bfloat16(lrelu(acc[rg][cg][j] + bv));
      }
    }
  }
}

// Fused RGCN conv, 32-row blocks: Out = X@root + mean_r0@rw0 + mean_r1@rw1 + bias.
// Both rels in one 32KB fp32 LDS tile (vrows 0-31 rel0, 32-63 rel1).
// Gather = ownership items (vrow, 8-col chunk), 4 cursors/thread, batched 8-deep with a
// __builtin_amdgcn_sched_barrier(0) PINNING the load cluster: R5-R9's source-level
// pipelines all got re-serialized by the scheduler (VGPR 36-68, depth~1, conv pinned at
// 155-175us). The barrier forbids sinking loads past it / hoisting consumers above it,
// forcing 8 outstanding vmem loads (counted vmcnt waits). Common case (all edges staged
// in LDS, ELCAP=2048 >> ~192 typical) runs a BRANCH-FREE word fetch (clamped LDS index,
// always a valid edge word; masked-off lanes multiply by 0). Hub blocks take the global
// fallback path.
// TAIL=true fuses lrelu(conv@Wo1^T+bO1)@Wo2^T+bo2 -> out2.
#define ELCAP 2048
template <bool TAIL>
__global__ __launch_bounds__(256, 3) void mfma_conv_f(
    const bf16* __restrict__ X, const int* __restrict__ off, const int* __restrict__ cnt,
    const int* __restrict__ elist, const float* __restrict__ inv,
    const bf16* __restrict__ WB, const float* __restrict__ bias, bf16* __restrict__ Out,
    const bf16* __restrict__ Wo1B, const float* __restrict__ bO1,
    const float* __restrict__ Wo2, const float* __restrict__ bo2,
    float* __restrict__ out2, int M, int NNr, int NEr) {
  __shared__ __align__(16) float At[64 * 128];
  __shared__ int eLs[ELCAP];
  int t = threadIdx.x;
  int wv = t >> 6, l = t & 63;
  int lr = l & 15, lg = l >> 4;
  int i0 = blockIdx.x * 32;
  int cbase = wv * 32;
  int ko = lg * 8;

  int iend = (i0 + 32 < M) ? i0 + 32 : M;
  int e0a = off[i0];
  int n0 = off[iend - 1] + cnt[iend - 1] - e0a;
  int e0b = off[NNr + i0];
  int n1 = off[NNr + iend - 1] + cnt[NNr + iend - 1] - e0b;
  int staged = n0 + n1 < ELCAP ? n0 + n1 : ELCAP;

  // ---- stage elist slices to LDS (coalesced; both rels contiguous CSR ranges) ----
  for (int k = t; k < staged; k += 256)
    eLs[k] = (k < n0) ? elist[e0a + k] : elist[e0b + (k - n0)];

  // cursors: pn=0,1 -> rel0 rows grp, grp+16; pn=2,3 -> rel1 rows grp, grp+16
  int grp = t >> 4;
  int c8 = (t & 15) * 8;
  int stc[4], dgc[4], lbase[4];
#pragma unroll
  for (int pn = 0; pn < 4; pn++) {
    int vr = grp + pn * 16;
    int rel = vr >> 5, m = vr & 31;
    int node = i0 + m;
    bool ok = node < M;
    int idx = rel * NNr + node;
    int so = ok ? off[idx] : 0;
    stc[pn] = so;
    dgc[pn] = ok ? cnt[idx] : 0;
    lbase[pn] = ok ? (rel ? n0 + (so - e0b) : so - e0a) : 0;
  }
  __syncthreads();

  // ---- batched gather: 8 words -> 8 pinned loads -> masked accumulate ----
  float s[4][8] = {};
  {
    int dmax = max(max(dgc[0], dgc[1]), max(dgc[2], dgc[3]));
    if (n0 + n1 <= ELCAP) {
      // branch-free common case: every word fetch is a clamped LDS read
      for (int e0 = 0; e0 < dmax; e0 += 2) {
        unsigned wbuf[8];
#pragma unroll
        for (int pn = 0; pn < 4; pn++) {
          int hi = dgc[pn] - 1;
          int ec0 = e0 < hi ? e0 : hi;
          ec0 = ec0 < 0 ? 0 : ec0;
          int ec1 = e0 + 1 < hi ? e0 + 1 : hi;
          ec1 = ec1 < 0 ? 0 : ec1;
          int li0 = lbase[pn] + ec0;
          int li1 = lbase[pn] + ec1;
          li0 = li0 < staged - 1 ? li0 : staged - 1;
          li1 = li1 < staged - 1 ? li1 : staged - 1;
          wbuf[2 * pn] = (unsigned)eLs[li0];
          wbuf[2 * pn + 1] = (unsigned)eLs[li1];
        }
        bfv8 v[8];
#pragma unroll
        for (int q = 0; q < 8; q++)
          v[q] = *(const bfv8*)&X[(size_t)(wbuf[q] & 0xFFFFFF) * 128 + c8];
        __builtin_amdgcn_sched_barrier(0);  // pin: all 8 loads issue before any use
#pragma unroll
        for (int pn = 0; pn < 4; pn++) {
          float m0 = e0 < dgc[pn] ? 1.f : 0.f;
          float m1 = e0 + 1 < dgc[pn] ? 1.f : 0.f;
#pragma unroll
          for (int j = 0; j < 8; j++)
            s[pn][j] +=
                m0 * __bfloat162float(v[2 * pn][j]) + m1 * __bfloat162float(v[2 * pn + 1][j]);
        }
      }
    } else {
      // hub fallback: word fetch may hit global elist
      auto eword = [&](int pn, int e) -> unsigned {
        int ec = e < dgc[pn] - 1 ? e : dgc[pn] - 1;
        ec = ec < 0 ? 0 : ec;
        int li = lbase[pn] + ec;
        if (li < staged) return (unsigned)eLs[li];
        int g = stc[pn] + ec;
        g = g < NEr - 1 ? g : NEr - 1;
        return (unsigned)elist[g];
      };
      for (int e0 = 0; e0 < dmax; e0 += 2) {
        unsigned wbuf[8];
#pragma unroll
        for (int pn = 0; pn < 4; pn++) {
          wbuf[2 * pn] = eword(pn, e0);
          wbuf[2 * pn + 1] = eword(pn, e0 + 1);
        }
        bfv8 v[8];
#pragma unroll
        for (int q = 0; q < 8; q++)
          v[q] = *(const bfv8*)&X[(size_t)(wbuf[q] & 0xFFFFFF) * 128 + c8];
        __builtin_amdgcn_sched_barrier(0);
#pragma unroll
        for (int pn = 0; pn < 4; pn++) {
          float m0 = e0 < dgc[pn] ? 1.f : 0.f;
          float m1 = e0 + 1 < dgc[pn] ? 1.f : 0.f;
#pragma unroll
          for (int j = 0; j < 8; j++)
            s[pn][j] +=
                m0 * __bfloat162float(v[2 * pn][j]) + m1 * __bfloat162float(v[2 * pn + 1][j]);
        }
      }
    }
  }
#pragma unroll
  for (int pn = 0; pn < 4; pn++) {
    int vr = grp + pn * 16;
    int sw = (vr & 7) << 4;
    int lb = vr * 512 + c8 * 4;
    *(float4*)((char*)At + (lb ^ sw)) = make_float4(s[pn][0], s[pn][1], s[pn][2], s[pn][3]);
    *(float4*)((char*)At + ((lb + 16) ^ sw)) =
        make_float4(s[pn][4], s[pn][5], s[pn][6], s[pn][7]);
  }

  // row clamps and inv scales
  size_t rowoff[2];
  float iv0[2], iv1[2];
#pragma unroll
  for (int rg = 0; rg < 2; rg++) {
    int row = i0 + rg * 16 + lr;
    int rc = row < M ? row : M - 1;
    rowoff[rg] = (size_t)rc * 128;
    iv0[rg] = row < M ? inv[row] : 0.f;
    iv1[rg] = row < M ? inv[NNr + row] : 0.f;
  }

  f32x4 acc[2][2] = {};

  // ---- seg 0: X @ root from global (overlaps gather LDS-store latency) ----
#pragma unroll
  for (int ks = 0; ks < 4; ks++) {
    bfv8 bk[2];
#pragma unroll
    for (int cg = 0; cg < 2; cg++)
      bk[cg] = *(const bfv8*)&WB[(size_t)(cbase + cg * 16 + lr) * 128 + ks * 32 + ko];
    bfv8 af[2];
#pragma unroll
    for (int rg = 0; rg < 2; rg++) af[rg] = *(const bfv8*)&X[rowoff[rg] + ks * 32 + ko];
#pragma unroll
    for (int rg = 0; rg < 2; rg++)
#pragma unroll
      for (int cg = 0; cg < 2; cg++)
        acc[rg][cg] =
            __builtin_amdgcn_mfma_f32_16x16x32_bf16(af[rg], bk[cg], acc[rg][cg], 0, 0, 0);
  }
  __syncthreads();

  // ---- rel-0 / rel-1 MFMA from LDS (inv-scaled, cvt to bf16) ----
#pragma unroll
  for (int r = 0; r < 2; r++) {
    const bf16* Wb = WB + 16384 * (1 + r);
#pragma unroll
    for (int ks = 0; ks < 4; ks++) {
      bfv8 bk[2];
#pragma unroll
      for (int cg = 0; cg < 2; cg++)
        bk[cg] = *(const bfv8*)&Wb[(size_t)(cbase + cg * 16 + lr) * 128 + ks * 32 + ko];
      bfv8 af[2];
#pragma unroll
      for (int rg = 0; rg < 2; rg++) {
        int mrow = r * 32 + rg * 16 + lr;
        int lb = mrow * 512 + ks * 128 + ko * 4;
        int sw = (mrow & 7) << 4;
        float4 f0 = *(const float4*)((const char*)At + (lb ^ sw));
        float4 f1 = *(const float4*)((const char*)At + ((lb + 16) ^ sw));
        float iv = r ? iv1[rg] : iv0[rg];
        bfv8 a;
        a[0] = (__bf16)(f0.x * iv); a[1] = (__bf16)(f0.y * iv);
        a[2] = (__bf16)(f0.z * iv); a[3] = (__bf16)(f0.w * iv);
        a[4] = (__bf16)(f1.x * iv); a[5] = (__bf16)(f1.y * iv);
        a[6] = (__bf16)(f1.z * iv); a[7] = (__bf16)(f1.w * iv);
        af[rg] = a;
      }
#pragma unroll
      for (int rg = 0; rg < 2; rg++)
#pragma unroll
        for (int cg = 0; cg < 2; cg++)
          acc[rg][cg] =
              __builtin_amdgcn_mfma_f32_16x16x32_bf16(af[rg], bk[cg], acc[rg][cg], 0, 0, 0);
    }
  }

  if (!TAIL) {
#pragma unroll
    for (int cg = 0; cg < 2; cg++) {
      int col = cbase + cg * 16 + lr;
      float bv = bias[col];
#pragma unroll
      for (int rg = 0; rg < 2; rg++) {
        int row0 = i0 + rg * 16 + lg * 4;
#pragma unroll
        for (int j = 0; j < 4; j++) {
          int row = row0 + j;
          if (row < M) Out[(size_t)row * 128 + col] = __float2bfloat16(acc[rg][cg][j] + bv);
        }
      }
    }
  } else {
    // ---- fused tail: y = conv_out + bias (bf16, LDS, swizzled) ----
    __syncthreads();  // all At reads done before overwrite
#pragma unroll
    for (int cg = 0; cg < 2; cg++) {
      int col = cbase + cg * 16 + lr;
      float bv = bias[col];
#pragma unroll
      for (int rg = 0; rg < 2; rg++) {
#pragma unroll
        for (int j = 0; j < 4; j++) {
          int row32 = rg * 16 + lg * 4 + j;
          int byte = row32 * 256 + col * 2;
          *(bf16*)((char*)At + (byte ^ ((row32 & 7) << 4))) =
              __float2bfloat16(acc[rg][cg][j] + bv);
        }
      }
    }
    __syncthreads();

    // z = lrelu(y @ Wo1^T + bO1): 32 rows x 128 cols
    f32x4 acc2[2][2] = {};
#pragma unroll
    for (int ks = 0; ks < 4; ks++) {
      bfv8 bk[2];
#pragma unroll
      for (int cg = 0; cg < 2; cg++)
        bk[cg] = *(const bfv8*)&Wo1B[(size_t)(cbase + cg * 16 + lr) * 128 + ks * 32 + ko];
      bfv8 af[2];
#pragma unroll
      for (int rg = 0; rg < 2; rg++) {
        int mrow = rg * 16 + lr;
        int byte = mrow * 256 + (ks * 32 + ko) * 2;
        af[rg] = *(const bfv8*)((const char*)At + (byte ^ ((mrow & 7) << 4)));
      }
#pragma unroll
      for (int rg = 0; rg < 2; rg++)
#pragma unroll
        for (int cg = 0; cg < 2; cg++)
          acc2[rg][cg] =
              __builtin_amdgcn_mfma_f32_16x16x32_bf16(af[rg], bk[cg], acc2[rg][cg], 0, 0, 0);
    }
    // store z (bf16, LDS bytes [8192,16384), no swizzle)
#pragma unroll
    for (int cg = 0; cg < 2; cg++) {
      int col = cbase + cg * 16 + lr;
      float bv = bO1[col];
#pragma unroll
      for (int rg = 0; rg < 2; rg++) {
#pragma unroll
        for (int j = 0; j < 4; j++) {
          int row32 = rg * 16 + lg * 4 + j;
          *(bf16*)((char*)At + 8192 + row32 * 256 + col * 2) =
              __float2bfloat16(lrelu(acc2[rg][cg][j] + bv));
        }
      }
    }
    __syncthreads();

    // out2[row] = z_row @ Wo2^T + bo2; 8 threads per row, shuffle-reduce
    int row = t >> 3, seg = t & 7;
    const bf16* zr = (const bf16*)((const char*)At + 8192 + row * 256 + seg * 32);
    float p0 = 0.f, p1 = 0.f;
#pragma unroll
    for (int q = 0; q < 16; q++) {
      float xv = __bfloat162float(zr[q]);
      int col = seg * 16 + q;
      p0 += xv * Wo2[col];
      p1 += xv * Wo2[128 + col];
    }
#pragma unroll
    for (int o = 4; o; o >>= 1) {
      p0 += __shfl_down(p0, o, 8);
      p1 += __shfl_down(p1, o, 8);
    }
    int grow = i0 + row;
    if (seg == 0 && grow < M) {
      out2[(size_t)grow * 2] = p0 + bo2[0];
      out2[(size_t)grow * 2 + 1] = p1 + bo2[1];
    }
  }
}

// ---------------- pipeline (bf16 storage, MFMA everywhere, fused ends) ----------------
static void run_pipeline(void* const* d_in, const int* S, float* out, char* ws,
                         int NUr, int NTr, int NEr, int dDes, int dNum, int dCat, int dTw,
                         hipStream_t stream) {
  const int NNr = NUr + NTr;
  const size_t xbytes = (size_t)NNr * 128 * 2;

  bf16* xa = (bf16*)ws;
  bf16* xb = (bf16*)(ws + xbytes);
  char* p = ws + 2 * xbytes;
  int* cnt = (int*)p;      p += (size_t)2 * NNr * 4;
  int* fill = (int*)p;     p += (size_t)2 * NNr * 4;  // contiguous with cnt
  int* off = (int*)p;      p += (size_t)2 * NNr * 4;
  int* bsum = (int*)p;     p += 2048 * 4;             // contiguous with bsumsc
  int* bsumsc = (int*)p;   p += 2048 * 4;
  float* inv = (float*)p;  p += (size_t)2 * NNr * 4;
  int* elist = (int*)p;    p += (size_t)NEr * 4;
  float* pw = (float*)p;   p += (size_t)PW_TOTAL * 4;
  int* flags = (int*)p;

  // ---- format probes: one launch ----
  ProbeArgs pa;
  for (int i = 0; i < 23; i++) {
    int src = (i == 22) ? 21 : i;  // b_o2 (2 elems) inherits W_o2's dtype
    pa.p[i] = d_in[src];
    if (i == 4) {
      pa.mode[i] = 1;
      pa.s[i] = NEr < 256 ? NEr : 256;
    } else if (i == 5) {
      pa.mode[i] = 1;
      int s2 = NEr / 2 < 256 ? NEr / 2 : 256;
      pa.s[i] = s2 < 1 ? 1 : s2;
    } else {
      pa.mode[i] = 0;
      int s = S[src] / 2;
      if (s > 256) s = 256;
      if (s < 1) s = 1;
      pa.s[i] = s;
    }
  }
  detect_all<<<23, 256, 0, stream>>>(pa, flags);
  prep_weights<<<(PW_W_TOTAL + 255) / 256, 256, 0, stream>>>(
      d_in[14], d_in[15], d_in[16], d_in[17], d_in[18], d_in[19], d_in[20], d_in[21],
      d_in[22], flags, pw);
  prep_enc<<<129, 256, 0, stream>>>(d_in[6], d_in[7], d_in[8], d_in[9], d_in[10], d_in[11],
                                    d_in[12], d_in[13], flags, dDes, dNum, dCat, dTw, pw);

  const float* bIn = pw + 81920;
  const float* rbp = pw + 82048;
  const float* bO1 = pw + 82176;
  const float* Wo2p = pw + 82304;
  const float* bo2p = pw + 82560;
  const bf16* WinB = (const bf16*)(pw + BF_BASE);
  const bf16* Wo1B = (const bf16*)(pw + BF_BASE + 8192);
  const bf16* ConvB = (const bf16*)(pw + BF_BASE + 16384);  // rootB, rwB0, rwB1
  const bf16* EncU = (const bf16*)(pw + ENC_BASE);
  const bf16* EncT = (const bf16*)(pw + ENC_BASE + 8192);
  const float* bU = pw + ENC_BASE + 16384;
  const float* bT = bU + 128;

  const void* ei = d_in[4];
  const void* et = d_in[5];
  const int nb1 = (2 * NNr + 1023) / 1024;

  // ---- CSR build ----
  zero_ints<<<(4 * NNr + 255) / 256, 256, 0, stream>>>(cnt, 4 * NNr);
  zero_ints<<<16, 256, 0, stream>>>(bsum, 4096);
  count_edges<<<(NEr + 255) / 256, 256, 0, stream>>>(ei, et, flags, cnt, NEr, NNr);
  scan_blocks<<<nb1, 256, 0, stream>>>(cnt, off, bsum, 2 * NNr);
  scan_blocks<<<1, 256, 0, stream>>>(bsum, bsumsc, nullptr, nb1);
  scan_add_inv<<<(2 * NNr + 255) / 256, 256, 0, stream>>>(off, bsumsc, cnt, inv, 2 * NNr);
  fill_elist<<<(NEr + 255) / 256, 256, 0, stream>>>(ei, et, flags, off, fill, elist, NEr, NNr);

  // ---- encoders (fused with W_in) -> xb ----
  if (dDes + dNum + dCat <= 128 && dTw <= 128) {
    enc_mfma<<<(NUr + 127) / 128, 256, 0, stream>>>(d_in[0], d_in[2], d_in[3], flags, 0, 2, 3,
                                                    dDes, dNum, dCat, EncU, bU, WinB, bIn, xb,
                                                    NUr, 0);
    enc_mfma<<<(NTr + 127) / 128, 256, 0, stream>>>(d_in[1], nullptr, nullptr, flags, 1, 1, 1,
                                                    dTw, 0, 0, EncT, bT, WinB, bIn, xb, NTr,
                                                    NUr);
  } else {
    enc_gemm<<<(NUr + 63) / 64, 256, 0, stream>>>(d_in[0], d_in[6], d_in[7], flags, 0, 6, 7,
                                                  xa, NUr, dDes, 64, 0, 0);
    enc_gemm<<<(NUr + 63) / 64, 256, 0, stream>>>(d_in[2], d_in[8], d_in[9], flags, 2, 8, 9,
                                                  xa, NUr, dNum, 32, 0, 64);
    enc_gemm<<<(NUr + 63) / 64, 256, 0, stream>>>(d_in[3], d_in[10], d_in[11], flags, 3, 10,
                                                  11, xa, NUr, dCat, 32, 0, 96);
    enc_gemm<<<(NTr + 63) / 64, 256, 0, stream>>>(d_in[1], d_in[12], d_in[13], flags, 1, 12,
                                                  13, xa, NTr, dTw, 128, NUr, 0);
    mfma_lin<<<(NNr + 127) / 128, 256, 0, stream>>>(xa, WinB, bIn, xb, NNr);
  }

  const int mt32 = (NNr + 31) / 32;
  mfma_conv_f<false><<<mt32, 256, 0, stream>>>(xb, off, cnt, elist, inv, ConvB, rbp, xa,
                                               nullptr, nullptr, nullptr, nullptr, nullptr,
                                               NNr, NNr, NEr);
  mfma_conv_f<true><<<mt32, 256, 0, stream>>>(xa, off, cnt, elist, inv, ConvB, rbp, nullptr,
                                              Wo1B, bO1, Wo2p, bo2p, out, NNr, NNr, NEr);
}

extern "C" void kernel_launch(void* const* d_in, const int* in_sizes, int n_in,
                              void* d_out, int out_size, void* d_ws, size_t ws_size,
                              hipStream_t stream) {
  float* out = (float*)d_out;
  char* ws = (char*)d_ws;

  auto signal = [&](int k) {
    sig_fill<<<(out_size + 255) / 256, 256, 0, stream>>>(out, out_size, (float)(200 + k));
  };

  if (n_in != 23) { signal(1); return; }
  const int* S = in_sizes;
  if (S[7] != 64 || S[9] != 32 || S[11] != 32 || S[13] != 128) { signal(2); return; }
  if (S[15] != 128) { signal(3); return; }
  if (S[6] % 64 || S[8] % 32 || S[10] % 32 || S[12] % 128) { signal(4); return; }
  int dDes = S[6] / 64, dNum = S[8] / 32, dCat = S[10] / 32, dTw = S[12] / 128;
  if (dDes <= 0 || dTw <= 0 || S[0] % dDes || S[1] % dTw) { signal(5); return; }
  if (dDes > 101 || dNum > 101 || dCat > 101 || dTw > 101) { signal(4); return; }
  int NUr = S[0] / dDes, NTr = S[1] / dTw, NNr = NUr + NTr, NEr = S[5];
  if (S[2] != NUr * dNum || S[3] != NUr * dCat) { signal(5); return; }
  if (S[4] != 2 * NEr || NEr < 1024) { signal(6); return; }
  if (NNr >= (1 << 24)) { signal(6); return; }  // elist src-packing limit
  if (S[14] != 16384 || S[16] != 32768 || S[17] != 16384 || S[18] != 128 ||
      S[19] != 16384 || S[20] != 128 || S[21] != 256 || S[22] != 2) { signal(7); return; }
  if (out_size != NNr * 2) { signal(8); return; }

  const size_t smallBytes = (size_t)4 * ((size_t)2 * NNr * 4) + 2 * 2048 * 4 +
                            (size_t)NEr * 4 + (size_t)PW_TOTAL * 4 + 512;
  const size_t need = 2 * (size_t)NNr * 128 * 2 + smallBytes;

  if (ws_size >= need) {
    run_pipeline(d_in, S, out, ws, NUr, NTr, NEr, dDes, dNum, dCat, dTw, stream);
  } else {
    signal(9);
  }
}

// Round 11
// 491.103 us; speedup vs baseline: 1.3195x; 1.0551x over previous
//
#include <hip/hip_runtime.h>
#include <hip/hip_bf16.h>

typedef __hip_bfloat16 bf16;

typedef __bf16 bfv8 __attribute__((ext_vector_type(8)));
typedef float f32x4 __attribute__((ext_vector_type(4)));

__device__ __forceinline__ float lrelu(float x) { return x > 0.f ? x : 0.01f * x; }

__device__ __forceinline__ float ldv(float v) { return v; }
__device__ __forceinline__ float ldv(bf16 v) { return __bfloat162float(v); }
__device__ __forceinline__ void stv(float* p, float v) { *p = v; }
__device__ __forceinline__ void stv(bf16* p, float v) { *p = __float2bfloat16(v); }

__device__ __forceinline__ float in_rd(const void* p, size_t i, int isbf) {
  return isbf ? __bfloat162float(((const bf16*)p)[i]) : ((const float*)p)[i];
}
__device__ __forceinline__ int ix_rd(const void* p, size_t i, int is64) {
  return is64 ? (int)((const long long*)p)[i] : ((const int*)p)[i];
}

// ---------------- fused per-array format probe: one launch, 23 blocks ----------------
struct ProbeArgs {
  const void* p[23];
  int s[23];
  int mode[23];
};

__global__ void detect_all(ProbeArgs a, int* __restrict__ flags) {
  __shared__ int sh[256];
  int b = blockIdx.x;
  const unsigned int* w = (const unsigned int*)a.p[b];
  int s = a.s[b], mode = a.mode[b];
  int t = threadIdx.x;
  int c = 0;
  if (t < s) {
    if (mode == 0) {
      unsigned int v = w[t];
      int e = (v >> 7) & 0xFF;
      c = (e >= 100 && e <= 140) ? 1 : 0;
    } else {
      c = (w[2 * t + 1] == 0u) ? 1 : 0;
    }
  }
  sh[t] = c;
  __syncthreads();
  for (int d = 128; d; d >>= 1) {
    if (t < d) sh[t] += sh[t + d];
    __syncthreads();
  }
  if (t == 0) flags[b] = (mode == 0) ? (sh[0] * 10 >= 7 * s) : (sh[0] * 10 >= 9 * s);
}

// ---------------- fused setup: weight prep + encoder prep + cnt/fill zero ----------------
// fp32 region (floats): [0,16384) W_inT [k,n]; [16384,32768) W_o1T [k,n]; [32768,49152) root;
// [49152,81920) rw; [81920] b_in; [82048] rgcn_bias; [82176] b_o1; [82304] W_o2; [82560] b_o2
// bf16 region (float index BF_BASE): 5x [128][128] bf16 [out][in]:
//   m=0 WinB; m=1 Wo1B; m=2 rootB; m=3 rwB0; m=4 rwB1
// ENC region (float index ENC_BASE): EncU bf16[128][128] (block-diag [des|num|cat]);
//   EncT bf16[128][128]; biasU[128]; biasT[128]
#define PW_F32 82562
#define BF_BASE 82564
#define PW_W_TOTAL (BF_BASE + 5 * 8192)
#define ENC_BASE PW_W_TOTAL
#define ENC_N 33024
#define PW_TOTAL (ENC_BASE + 16384 + 256)
__global__ void setup_all(const void* Win, const void* bin, const void* rw, const void* root,
                          const void* rb, const void* Wo1, const void* bo1, const void* Wo2,
                          const void* bo2, const void* Wd, const void* bd, const void* Wn,
                          const void* bn, const void* Wc, const void* bc, const void* Wt,
                          const void* bt, const int* __restrict__ fl, int dDes, int dNum,
                          int dCat, int dTw, float* __restrict__ pw, int* __restrict__ cnt4,
                          int NNr) {
  int i = blockIdx.x * 256 + threadIdx.x;
  if (i < PW_W_TOTAL) {
    if (i < 16384) {
      int k = i >> 7, o = i & 127;
      pw[i] = in_rd(Win, (size_t)o * 128 + k, fl[14]);
    } else if (i < 32768) {
      int j = i - 16384;
      int k = j >> 7, o = j & 127;
      pw[i] = in_rd(Wo1, (size_t)o * 128 + k, fl[19]);
    } else if (i < 49152) {
      pw[i] = in_rd(root, i - 32768, fl[17]);
    } else if (i < 81920) {
      pw[i] = in_rd(rw, i - 49152, fl[16]);
    } else if (i < 82048) {
      pw[i] = in_rd(bin, i - 81920, fl[15]);
    } else if (i < 82176) {
      pw[i] = in_rd(rb, i - 82048, fl[18]);
    } else if (i < 82304) {
      pw[i] = in_rd(bo1, i - 82176, fl[20]);
    } else if (i < 82560) {
      pw[i] = in_rd(Wo2, i - 82304, fl[21]);
    } else if (i < PW_F32) {
      pw[i] = in_rd(bo2, i - 82560, fl[22]);
    } else if (i >= BF_BASE) {
      int j = i - BF_BASE;
      bf16* bw = (bf16*)(pw + BF_BASE);
#pragma unroll
      for (int q = 0; q < 2; q++) {
        int u = 2 * j + q;
        int m = u >> 14, r = u & 16383;
        int n = r >> 7, k = r & 127;
        float v;
        if (m == 0) v = in_rd(Win, (size_t)n * 128 + k, fl[14]);
        else if (m == 1) v = in_rd(Wo1, (size_t)n * 128 + k, fl[19]);
        else if (m == 2) v = in_rd(root, (size_t)k * 128 + n, fl[17]);
        else v = in_rd(rw, (size_t)(m - 3) * 16384 + (size_t)k * 128 + n, fl[16]);
        bw[u] = __float2bfloat16(v);
      }
    }
  } else if (i < PW_W_TOTAL + ENC_N) {
    int j = i - PW_W_TOTAL;
    bf16* e = (bf16*)(pw + ENC_BASE);
    float* bU = pw + ENC_BASE + 16384;
    float* bT = bU + 128;
    if (j < 16384) {
      int n = j >> 7, k = j & 127;
      float v = 0.f;
      if (n < 64) {
        if (k < dDes) v = in_rd(Wd, (size_t)n * dDes + k, fl[6]);
      } else if (n < 96) {
        int kk = k - dDes;
        if (kk >= 0 && kk < dNum) v = in_rd(Wn, (size_t)(n - 64) * dNum + kk, fl[8]);
      } else {
        int kk = k - dDes - dNum;
        if (kk >= 0 && kk < dCat) v = in_rd(Wc, (size_t)(n - 96) * dCat + kk, fl[10]);
      }
      e[j] = __float2bfloat16(v);
    } else if (j < 32768) {
      int j2 = j - 16384;
      int n = j2 >> 7, k = j2 & 127;
      float v = (k < dTw) ? in_rd(Wt, (size_t)n * dTw + k, fl[12]) : 0.f;
      e[j] = __float2bfloat16(v);
    } else if (j < 32896) {
      int j2 = j - 32768;
      bU[j2] = (j2 < 64) ? in_rd(bd, j2, fl[7])
                         : (j2 < 96) ? in_rd(bn, j2 - 64, fl[9]) : in_rd(bc, j2 - 96, fl[11]);
    } else {
      bT[j - 32896] = in_rd(bt, j - 32896, fl[13]);
    }
  } else {
    int j = i - PW_W_TOTAL - ENC_N;
    if (j < 4 * NNr) cnt4[j] = 0;  // cnt (2*NNr) + fill (2*NNr), contiguous
  }
}

// ---------------- utilities ----------------
__global__ void sig_fill(float* __restrict__ p, int n, float v) {
  int i = blockIdx.x * 256 + threadIdx.x;
  if (i < n) p[i] = v;
}

// ---------------- CSR build ----------------
__global__ void count_edges(const void* __restrict__ ei, const void* __restrict__ et,
                            const int* __restrict__ fl, int* __restrict__ cnt, int NEr,
                            int NNr) {
  int e = blockIdx.x * 256 + threadIdx.x;
  if (e >= NEr) return;
  int d = ix_rd(ei, (size_t)NEr + e, fl[4]);
  int r = ix_rd(et, e, fl[5]) & 1;
  if ((unsigned)d >= (unsigned)NNr) return;
  atomicAdd(&cnt[r * NNr + d], 1);
}

__global__ void scan_blocks(const int* __restrict__ in, int* __restrict__ out,
                            int* __restrict__ bsum, int n) {
  __shared__ int sh[256];
  int t = threadIdx.x;
  int base = blockIdx.x * 1024 + t * 4;
  int a[4];
  int s = 0;
#pragma unroll
  for (int i = 0; i < 4; i++) {
    a[i] = (base + i < n) ? in[base + i] : 0;
    s += a[i];
  }
  sh[t] = s;
  __syncthreads();
  for (int d = 1; d < 256; d <<= 1) {
    int v = (t >= d) ? sh[t - d] : 0;
    __syncthreads();
    sh[t] += v;
    __syncthreads();
  }
  int ex = sh[t] - s;
#pragma unroll
  for (int i = 0; i < 4; i++) {
    if (base + i < n) out[base + i] = ex;
    ex += a[i];
  }
  if (t == 255 && bsum) bsum[blockIdx.x] = sh[255];
}

__global__ void scan_add_inv(int* __restrict__ off, const int* __restrict__ bsumsc,
                             const int* __restrict__ cnt, float* __restrict__ inv, int n) {
  int i = blockIdx.x * 256 + threadIdx.x;
  if (i >= n) return;
  off[i] += bsumsc[i >> 10];
  inv[i] = 1.f / fmaxf((float)cnt[i], 1.f);
}

// elist word packs: bits [0,24) = src node id
__global__ void fill_elist(const void* __restrict__ ei, const void* __restrict__ et,
                           const int* __restrict__ fl, const int* __restrict__ off,
                           int* __restrict__ fill, int* __restrict__ elist, int NEr, int NNr) {
  int e = blockIdx.x * 256 + threadIdx.x;
  if (e >= NEr) return;
  int s = ix_rd(ei, e, fl[4]);
  int d = ix_rd(ei, (size_t)NEr + e, fl[4]);
  int r = ix_rd(et, e, fl[5]) & 1;
  if ((unsigned)d >= (unsigned)NNr || (unsigned)s >= (unsigned)NNr) return;
  int idx = r * NNr + d;
  int slot = off[idx] + atomicAdd(&fill[idx], 1);
  elist[slot] = s | ((d & 127) << 24);
}

// ---------------- legacy encoder GEMM (fallback for oversized K) ----------------
__global__ __launch_bounds__(256) void enc_gemm(const void* __restrict__ A,
                                                const void* __restrict__ W,
                                                const void* __restrict__ B,
                                                const int* __restrict__ fl, int fa, int fw,
                                                int fb, bf16* __restrict__ x, int M, int K,
                                                int N, int row0, int col0) {
  __shared__ float Wb[128 * 102];
  __shared__ float bb[128];
  int t = threadIdx.x;
  int stride = (K & 1) ? K : K + 1;
  int fA = fl[fa];
  {
    int fW = fl[fw], fB = fl[fb];
    for (int idx = t; idx < N * K; idx += 256) {
      int j = idx / K, k = idx - j * K;
      Wb[j * stride + k] = in_rd(W, (size_t)j * K + k, fW);
    }
    if (t < N) bb[t] = in_rd(B, t, fB);
  }
  __syncthreads();
  int j = t % N;
  int r = t / N;
  int R = 256 / N;
  int iEnd = blockIdx.x * 64 + 64;
  if (iEnd > M) iEnd = M;
  const float* wrow = &Wb[j * stride];
  if (!fA) {
    const float* Af = (const float*)A;
    for (int i = blockIdx.x * 64 + r; i < iEnd; i += R) {
      const float* a = Af + (size_t)i * K;
      float acc = bb[j];
      for (int k = 0; k < K; k++) acc += a[k] * wrow[k];
      stv(&x[(size_t)(row0 + i) * 128 + col0 + j], lrelu(acc));
    }
  } else {
    const bf16* Ab = (const bf16*)A;
    for (int i = blockIdx.x * 64 + r; i < iEnd; i += R) {
      const bf16* a = Ab + (size_t)i * K;
      float acc = bb[j];
      for (int k = 0; k < K; k++) acc += __bfloat162float(a[k]) * wrow[k];
      stv(&x[(size_t)(row0 + i) * 128 + col0 + j], lrelu(acc));
    }
  }
}

// ================= MFMA GEMMs (bf16 storage, fp32 accumulate) =================
// v_mfma_f32_16x16x32_bf16 fragments (m89/m91-verified C/D mapping):
//   A: lane l holds A[m = l&15][k = (l>>4)*8 + i]
//   B: lane l holds B[k = (l>>4)*8 + i][n = l&15]  (= Wt[n][k], Wt in [out][in] layout)
//   D: lane l reg j -> row = (l>>4)*4 + j, col = l&15

// Fused MFMA encoder: input segs -> LDS bf16 tile (VECTORIZED staging: the block's input
// window is flat-contiguous, so load float4 / ushort4 = 4 elements per instruction with a
// scalar-clamped tail; 4x fewer global load instrs than R10's scalar staging) ->
// enc MFMA + lrelu -> LDS -> W_in MFMA + lrelu -> global.
// LDS rows XOR-swizzled (byte ^= (row&7)<<4).
__global__ __launch_bounds__(256) void enc_mfma(
    const void* __restrict__ A0, const void* __restrict__ A1, const void* __restrict__ A2,
    const int* __restrict__ fl, int fi0, int fi1, int fi2, int K0, int K1, int K2,
    const bf16* __restrict__ WbE, const float* __restrict__ biasE,
    const bf16* __restrict__ WbL, const float* __restrict__ bL, bf16* __restrict__ x,
    int M, int row0) {
  __shared__ __align__(16) bf16 Xs[16384];
  int t = threadIdx.x;
  int i0 = blockIdx.x * 128;

  {
    uint4 z = {0u, 0u, 0u, 0u};
#pragma unroll
    for (int i = 0; i < 8; i++) *(uint4*)((char*)Xs + i * 4096 + t * 16) = z;
  }
  __syncthreads();

  const void* As[3] = {A0, A1, A2};
  int Ks_[3] = {K0, K1, K2};
  int fis[3] = {fi0, fi1, fi2};
  int cb = 0;
  for (int s = 0; s < 3; s++) {
    int Ks = Ks_[s];
    if (Ks <= 0) continue;
    int isbf = fl[fis[s]];
    int total = 128 * Ks;
    long gml = (long)(M - i0) * Ks;
    int gmax = gml > total ? total : (gml < 0 ? 0 : (int)gml);
    int nu = (total + 3) >> 2;
    if (!isbf) {
      const float* Af = (const float*)As[s] + (size_t)i0 * Ks;
      for (int u = t; u < nu; u += 256) {
        int f0 = u * 4;
        float vv[4];
        if (f0 + 4 <= gmax) {
          float4 x4 = *(const float4*)(Af + f0);  // 16B aligned: i0*Ks and f0 mult of 4
          vv[0] = x4.x; vv[1] = x4.y; vv[2] = x4.z; vv[3] = x4.w;
        } else {
          vv[0] = (f0 < gmax) ? Af[f0] : 0.f;
          vv[1] = (f0 + 1 < gmax) ? Af[f0 + 1] : 0.f;
          vv[2] = (f0 + 2 < gmax) ? Af[f0 + 2] : 0.f;
          vv[3] = (f0 + 3 < gmax) ? Af[f0 + 3] : 0.f;
        }
#pragma unroll
        for (int q = 0; q < 4; q++) {
          int f = f0 + q;
          if (f < total) {
            int row = f / Ks, k = f - row * Ks;
            int byte = row * 256 + (cb + k) * 2;
            *(bf16*)((char*)Xs + (byte ^ ((row & 7) << 4))) = __float2bfloat16(vv[q]);
          }
        }
      }
    } else {
      const unsigned short* Ab = (const unsigned short*)As[s] + (size_t)i0 * Ks;
      for (int u = t; u < nu; u += 256) {
        int f0 = u * 4;
        unsigned short vv[4];
        if (f0 + 4 <= gmax) {
          ushort4 x4 = *(const ushort4*)(Ab + f0);  // 8B aligned
          vv[0] = x4.x; vv[1] = x4.y; vv[2] = x4.z; vv[3] = x4.w;
        } else {
          vv[0] = (f0 < gmax) ? Ab[f0] : 0;
          vv[1] = (f0 + 1 < gmax) ? Ab[f0 + 1] : 0;
          vv[2] = (f0 + 2 < gmax) ? Ab[f0 + 2] : 0;
          vv[3] = (f0 + 3 < gmax) ? Ab[f0 + 3] : 0;
        }
#pragma unroll
        for (int q = 0; q < 4; q++) {
          int f = f0 + q;
          if (f < total) {
            int row = f / Ks, k = f - row * Ks;
            int byte = row * 256 + (cb + k) * 2;
            *(unsigned short*)((char*)Xs + (byte ^ ((row & 7) << 4))) = vv[q];
          }
        }
      }
    }
    cb += Ks;
  }
  __syncthreads();

  int wv = t >> 6, l = t & 63;
  int lr = l & 15, lg = l >> 4;
  int rbase = (wv >> 1) * 64, cbase = (wv & 1) * 64;
  int ko = lg * 8;
  f32x4 acc[4][4] = {};
#pragma unroll
  for (int ks = 0; ks < 4; ks++) {
    bfv8 bk[4];
#pragma unroll
    for (int cg = 0; cg < 4; cg++)
      bk[cg] = *(const bfv8*)&WbE[(size_t)(cbase + cg * 16 + lr) * 128 + ks * 32 + ko];
    bfv8 af[4];
#pragma unroll
    for (int rg = 0; rg < 4; rg++) {
      int mrow = rbase + rg * 16 + lr;
      int byte = mrow * 256 + (ks * 32 + ko) * 2;
      af[rg] = *(const bfv8*)((const char*)Xs + (byte ^ ((mrow & 7) << 4)));
    }
#pragma unroll
    for (int rg = 0; rg < 4; rg++)
#pragma unroll
      for (int cg = 0; cg < 4; cg++)
        acc[rg][cg] =
            __builtin_amdgcn_mfma_f32_16x16x32_bf16(af[rg], bk[cg], acc[rg][cg], 0, 0, 0);
  }
  __syncthreads();

#pragma unroll
  for (int cg = 0; cg < 4; cg++) {
    int col = cbase + cg * 16 + lr;
    float bv = biasE[col];
#pragma unroll
    for (int rg = 0; rg < 4; rg++) {
      int r0 = rbase + rg * 16 + lg * 4;
#pragma unroll
      for (int j = 0; j < 4; j++) {
        int row = r0 + j;
        int byte = row * 256 + col * 2;
        *(bf16*)((char*)Xs + (byte ^ ((row & 7) << 4))) =
            __float2bfloat16(lrelu(acc[rg][cg][j] + bv));
      }
    }
  }
  __syncthreads();

  f32x4 acc2[4][4] = {};
#pragma unroll
  for (int ks = 0; ks < 4; ks++) {
    bfv8 bk[4];
#pragma unroll
    for (int cg = 0; cg < 4; cg++)
      bk[cg] = *(const bfv8*)&WbL[(size_t)(cbase + cg * 16 + lr) * 128 + ks * 32 + ko];
    bfv8 af[4];
#pragma unroll
    for (int rg = 0; rg < 4; rg++) {
      int mrow = rbase + rg * 16 + lr;
      int byte = mrow * 256 + (ks * 32 + ko) * 2;
      af[rg] = *(const bfv8*)((const char*)Xs + (byte ^ ((mrow & 7) << 4)));
    }
#pragma unroll
    for (int rg = 0; rg < 4; rg++)
#pragma unroll
      for (int cg = 0; cg < 4; cg++)
        acc2[rg][cg] =
            __builtin_amdgcn_mfma_f32_16x16x32_bf16(af[rg], bk[cg], acc2[rg][cg], 0, 0, 0);
  }

#pragma unroll
  for (int cg = 0; cg < 4; cg++) {
    int col = cbase + cg * 16 + lr;
    float bv = bL[col];
#pragma unroll
    for (int rg = 0; rg < 4; rg++) {
      int r0 = i0 + rbase + rg * 16 + lg * 4;
#pragma unroll
      for (int j = 0; j < 4; j++) {
        int row = r0 + j;
        if (row < M)
          x[(size_t)(row0 + row) * 128 + col] = __float2bfloat16(lrelu(acc2[rg][cg][j] + bv));
      }
    }
  }
}

// Out = lrelu(A @ Wb^T + bias); fallback-path linear
__global__ __launch_bounds__(256) void mfma_lin(const bf16* __restrict__ A,
                                                const bf16* __restrict__ Wb,
                                                const float* __restrict__ bias,
                                                bf16* __restrict__ Out, int M) {
  int t = threadIdx.x;
  int wv = t >> 6, l = t & 63;
  int lr = l & 15, lg = l >> 4;
  int i0 = blockIdx.x * 128;
  int rbase = (wv >> 1) * 64;
  int cbase = (wv & 1) * 64;
  int ko = lg * 8;

  size_t rowoff[4];
#pragma unroll
  for (int rg = 0; rg < 4; rg++) {
    int row = i0 + rbase + rg * 16 + lr;
    if (row > M - 1) row = M - 1;
    rowoff[rg] = (size_t)row * 128;
  }

  bfv8 bfr[4][4];
#pragma unroll
  for (int cg = 0; cg < 4; cg++)
#pragma unroll
    for (int ks = 0; ks < 4; ks++)
      bfr[cg][ks] = *(const bfv8*)&Wb[(size_t)(cbase + cg * 16 + lr) * 128 + ks * 32 + ko];

  f32x4 acc[4][4] = {};
#pragma unroll
  for (int ks = 0; ks < 4; ks++) {
    bfv8 af[4];
#pragma unroll
    for (int rg = 0; rg < 4; rg++) af[rg] = *(const bfv8*)&A[rowoff[rg] + ks * 32 + ko];
#pragma unroll
    for (int rg = 0; rg < 4; rg++)
#pragma unroll
      for (int cg = 0; cg < 4; cg++)
        acc[rg][cg] =
            __builtin_amdgcn_mfma_f32_16x16x32_bf16(af[rg], bfr[cg][ks], acc[rg][cg], 0, 0, 0);
  }

#pragma unroll
  for (int cg = 0; cg < 4; cg++) {
    int col = cbase + cg * 16 + lr;
    float bv = bias[col];
#pragma unroll
    for (int rg = 0; rg < 4; rg++) {
      int row0 = i0 + rbase + rg * 16 + lg * 4;
#pragma unroll
      for (int j = 0; j < 4; j++) {
        int row = row0 + j;
        if (row < M) Out[(size_t)row * 128 + col] = __float2bfloat16(lrelu(acc[rg][cg][j] + bv));
      }
    }
  }
}

// Fused RGCN conv, 32-row blocks: Out = X@root + mean_r0@rw0 + mean_r1@rw1 + bias.
// Both rels in one 32KB fp32 LDS tile (vrows 0-31 rel0, 32-63 rel1).
// Gather = R6 structure (best measured across 6 variants: 155us vs 162-244 for atomics/
// staged/pinned variants; the ~160us/conv cost is invariant to code shape -> scattered
// LLC-transaction ceiling for 600K random 256B row reads, X=51MB >> 4MB/XCD L2).
// Joint 4-cursor walk with depth-2 lookahead; elist read from global (L2-hot).
// TAIL=true fuses lrelu(conv@Wo1^T+bO1)@Wo2^T+bo2 -> out2.
template <bool TAIL>
__global__ __launch_bounds__(256, 4) void mfma_conv_f(
    const bf16* __restrict__ X, const int* __restrict__ off, const int* __restrict__ cnt,
    const int* __restrict__ elist, const float* __restrict__ inv,
    const bf16* __restrict__ WB, const float* __restrict__ bias, bf16* __restrict__ Out,
    const bf16* __restrict__ Wo1B, const float* __restrict__ bO1,
    const float* __restrict__ Wo2, const float* __restrict__ bo2,
    float* __restrict__ out2, int M, int NNr) {
  __shared__ __align__(16) float At[64 * 128];
  int t = threadIdx.x;
  int wv = t >> 6, l = t & 63;
  int lr = l & 15, lg = l >> 4;
  int i0 = blockIdx.x * 32;
  int cbase = wv * 32;
  int ko = lg * 8;

  // ---- joint 4-cursor ownership gather (depth-2 lookahead) ----
  {
    int grp = t >> 4;
    int c8 = (t & 15) * 8;
    int stc[4], dgc[4];
#pragma unroll
    for (int pn = 0; pn < 4; pn++) {
      int vr = grp + pn * 16;  // 0..63
      int rel = vr >> 5, m = vr & 31;
      int node = i0 + m;
      bool ok = node < M;
      int idx = rel * NNr + node;
      stc[pn] = ok ? off[idx] : 0;
      dgc[pn] = ok ? cnt[idx] : 0;
    }
    int dmax = max(max(dgc[0], dgc[1]), max(dgc[2], dgc[3]));
    float s[4][8] = {};
    bfv8 v[4];
#pragma unroll
    for (int pn = 0; pn < 4; pn++) {
      if (dgc[pn] > 0) {
        int src = elist[stc[pn]] & 0xFFFFFF;
        v[pn] = *(const bfv8*)&X[(size_t)src * 128 + c8];
      }
    }
    for (int e = 0; e < dmax; e++) {
      bfv8 nv[4];
#pragma unroll
      for (int pn = 0; pn < 4; pn++) {
        if (e + 1 < dgc[pn]) {
          int src = elist[stc[pn] + e + 1] & 0xFFFFFF;
          nv[pn] = *(const bfv8*)&X[(size_t)src * 128 + c8];
        }
      }
#pragma unroll
      for (int pn = 0; pn < 4; pn++) {
        if (e < dgc[pn]) {
#pragma unroll
          for (int j = 0; j < 8; j++) s[pn][j] += __bfloat162float(v[pn][j]);
        }
      }
#pragma unroll
      for (int pn = 0; pn < 4; pn++) v[pn] = nv[pn];
    }
#pragma unroll
    for (int pn = 0; pn < 4; pn++) {
      int vr = grp + pn * 16;
      int sw = (vr & 7) << 4;
      int lb = vr * 512 + c8 * 4;
      *(float4*)((char*)At + (lb ^ sw)) = make_float4(s[pn][0], s[pn][1], s[pn][2], s[pn][3]);
      *(float4*)((char*)At + ((lb + 16) ^ sw)) =
          make_float4(s[pn][4], s[pn][5], s[pn][6], s[pn][7]);
    }
  }

  // row clamps and inv scales
  size_t rowoff[2];
  float iv0[2], iv1[2];
#pragma unroll
  for (int rg = 0; rg < 2; rg++) {
    int row = i0 + rg * 16 + lr;
    int rc = row < M ? row : M - 1;
    rowoff[rg] = (size_t)rc * 128;
    iv0[rg] = row < M ? inv[row] : 0.f;
    iv1[rg] = row < M ? inv[NNr + row] : 0.f;
  }

  f32x4 acc[2][2] = {};

  // ---- seg 0: X @ root from global (overlaps gather LDS-store latency) ----
#pragma unroll
  for (int ks = 0; ks < 4; ks++) {
    bfv8 bk[2];
#pragma unroll
    for (int cg = 0; cg < 2; cg++)
      bk[cg] = *(const bfv8*)&WB[(size_t)(cbase + cg * 16 + lr) * 128 + ks * 32 + ko];
    bfv8 af[2];
#pragma unroll
    for (int rg = 0; rg < 2; rg++) af[rg] = *(const bfv8*)&X[rowoff[rg] + ks * 32 + ko];
#pragma unroll
    for (int rg = 0; rg < 2; rg++)
#pragma unroll
      for (int cg = 0; cg < 2; cg++)
        acc[rg][cg] =
            __builtin_amdgcn_mfma_f32_16x16x32_bf16(af[rg], bk[cg], acc[rg][cg], 0, 0, 0);
  }
  __syncthreads();

  // ---- rel-0 / rel-1 MFMA from LDS (inv-scaled, cvt to bf16) ----
#pragma unroll
  for (int r = 0; r < 2; r++) {
    const bf16* Wb = WB + 16384 * (1 + r);
#pragma unroll
    for (int ks = 0; ks < 4; ks++) {
      bfv8 bk[2];
#pragma unroll
      for (int cg = 0; cg < 2; cg++)
        bk[cg] = *(const bfv8*)&Wb[(size_t)(cbase + cg * 16 + lr) * 128 + ks * 32 + ko];
      bfv8 af[2];
#pragma unroll
      for (int rg = 0; rg < 2; rg++) {
        int mrow = r * 32 + rg * 16 + lr;
        int lb = mrow * 512 + ks * 128 + ko * 4;
        int sw = (mrow & 7) << 4;
        float4 f0 = *(const float4*)((const char*)At + (lb ^ sw));
        float4 f1 = *(const float4*)((const char*)At + ((lb + 16) ^ sw));
        float iv = r ? iv1[rg] : iv0[rg];
        bfv8 a;
        a[0] = (__bf16)(f0.x * iv); a[1] = (__bf16)(f0.y * iv);
        a[2] = (__bf16)(f0.z * iv); a[3] = (__bf16)(f0.w * iv);
        a[4] = (__bf16)(f1.x * iv); a[5] = (__bf16)(f1.y * iv);
        a[6] = (__bf16)(f1.z * iv); a[7] = (__bf16)(f1.w * iv);
        af[rg] = a;
      }
#pragma unroll
      for (int rg = 0; rg < 2; rg++)
#pragma unroll
        for (int cg = 0; cg < 2; cg++)
          acc[rg][cg] =
              __builtin_amdgcn_mfma_f32_16x16x32_bf16(af[rg], bk[cg], acc[rg][cg], 0, 0, 0);
    }
  }

  if (!TAIL) {
#pragma unroll
    for (int cg = 0; cg < 2; cg++) {
      int col = cbase + cg * 16 + lr;
      float bv = bias[col];
#pragma unroll
      for (int rg = 0; rg < 2; rg++) {
        int row0 = i0 + rg * 16 + lg * 4;
#pragma unroll
        for (int j = 0; j < 4; j++) {
          int row = row0 + j;
          if (row < M) Out[(size_t)row * 128 + col] = __float2bfloat16(acc[rg][cg][j] + bv);
        }
      }
    }
  } else {
    // ---- fused tail: y = conv_out + bias (bf16, LDS, swizzled) ----
    __syncthreads();  // all At reads done before overwrite
#pragma unroll
    for (int cg = 0; cg < 2; cg++) {
      int col = cbase + cg * 16 + lr;
      float bv = bias[col];
#pragma unroll
      for (int rg = 0; rg < 2; rg++) {
#pragma unroll
        for (int j = 0; j < 4; j++) {
          int row32 = rg * 16 + lg * 4 + j;
          int byte = row32 * 256 + col * 2;
          *(bf16*)((char*)At + (byte ^ ((row32 & 7) << 4))) =
              __float2bfloat16(acc[rg][cg][j] + bv);
        }
      }
    }
    __syncthreads();

    // z = lrelu(y @ Wo1^T + bO1): 32 rows x 128 cols
    f32x4 acc2[2][2] = {};
#pragma unroll
    for (int ks = 0; ks < 4; ks++) {
      bfv8 bk[2];
#pragma unroll
      for (int cg = 0; cg < 2; cg++)
        bk[cg] = *(const bfv8*)&Wo1B[(size_t)(cbase + cg * 16 + lr) * 128 + ks * 32 + ko];
      bfv8 af[2];
#pragma unroll
      for (int rg = 0; rg < 2; rg++) {
        int mrow = rg * 16 + lr;
        int byte = mrow * 256 + (ks * 32 + ko) * 2;
        af[rg] = *(const bfv8*)((const char*)At + (byte ^ ((mrow & 7) << 4)));
      }
#pragma unroll
      for (int rg = 0; rg < 2; rg++)
#pragma unroll
        for (int cg = 0; cg < 2; cg++)
          acc2[rg][cg] =
              __builtin_amdgcn_mfma_f32_16x16x32_bf16(af[rg], bk[cg], acc2[rg][cg], 0, 0, 0);
    }
    // store z (bf16, LDS bytes [8192,16384), no swizzle)
#pragma unroll
    for (int cg = 0; cg < 2; cg++) {
      int col = cbase + cg * 16 + lr;
      float bv = bO1[col];
#pragma unroll
      for (int rg = 0; rg < 2; rg++) {
#pragma unroll
        for (int j = 0; j < 4; j++) {
          int row32 = rg * 16 + lg * 4 + j;
          *(bf16*)((char*)At + 8192 + row32 * 256 + col * 2) =
              __float2bfloat16(lrelu(acc2[rg][cg][j] + bv));
        }
      }
    }
    __syncthreads();

    // out2[row] = z_row @ Wo2^T + bo2; 8 threads per row, shuffle-reduce
    int row = t >> 3, seg = t & 7;
    const bf16* zr = (const bf16*)((const char*)At + 8192 + row * 256 + seg * 32);
    float p0 = 0.f, p1 = 0.f;
#pragma unroll
    for (int q = 0; q < 16; q++) {
      float xv = __bfloat162float(zr[q]);
      int col = seg * 16 + q;
      p0 += xv * Wo2[col];
      p1 += xv * Wo2[128 + col];
    }
#pragma unroll
    for (int o = 4; o; o >>= 1) {
      p0 += __shfl_down(p0, o, 8);
      p1 += __shfl_down(p1, o, 8);
    }
    int grow = i0 + row;
    if (seg == 0 && grow < M) {
      out2[(size_t)grow * 2] = p0 + bo2[0];
      out2[(size_t)grow * 2 + 1] = p1 + bo2[1];
    }
  }
}

// ---------------- pipeline (bf16 storage, MFMA everywhere, fused ends) ----------------
static void run_pipeline(void* const* d_in, const int* S, float* out, char* ws,
                         int NUr, int NTr, int NEr, int dDes, int dNum, int dCat, int dTw,
                         hipStream_t stream) {
  const int NNr = NUr + NTr;
  const size_t xbytes = (size_t)NNr * 128 * 2;

  bf16* xa = (bf16*)ws;
  bf16* xb = (bf16*)(ws + xbytes);
  char* p = ws + 2 * xbytes;
  int* cnt = (int*)p;      p += (size_t)2 * NNr * 4;
  int* fill = (int*)p;     p += (size_t)2 * NNr * 4;  // contiguous with cnt
  int* off = (int*)p;      p += (size_t)2 * NNr * 4;
  int* bsum = (int*)p;     p += 2048 * 4;             // contiguous with bsumsc
  int* bsumsc = (int*)p;   p += 2048 * 4;
  float* inv = (float*)p;  p += (size_t)2 * NNr * 4;
  int* elist = (int*)p;    p += (size_t)NEr * 4;
  float* pw = (float*)p;   p += (size_t)PW_TOTAL * 4;
  int* flags = (int*)p;

  // ---- format probes: one launch ----
  ProbeArgs pa;
  for (int i = 0; i < 23; i++) {
    int src = (i == 22) ? 21 : i;  // b_o2 (2 elems) inherits W_o2's dtype
    pa.p[i] = d_in[src];
    if (i == 4) {
      pa.mode[i] = 1;
      pa.s[i] = NEr < 256 ? NEr : 256;
    } else if (i == 5) {
      pa.mode[i] = 1;
      int s2 = NEr / 2 < 256 ? NEr / 2 : 256;
      pa.s[i] = s2 < 1 ? 1 : s2;
    } else {
      pa.mode[i] = 0;
      int s = S[src] / 2;
      if (s > 256) s = 256;
      if (s < 1) s = 1;
      pa.s[i] = s;
    }
  }
  detect_all<<<23, 256, 0, stream>>>(pa, flags);

  // ---- fused setup: weight prep + enc prep + cnt/fill zero (one launch) ----
  const int setupN = PW_W_TOTAL + ENC_N + 4 * NNr;
  setup_all<<<(setupN + 255) / 256, 256, 0, stream>>>(
      d_in[14], d_in[15], d_in[16], d_in[17], d_in[18], d_in[19], d_in[20], d_in[21],
      d_in[22], d_in[6], d_in[7], d_in[8], d_in[9], d_in[10], d_in[11], d_in[12], d_in[13],
      flags, dDes, dNum, dCat, dTw, pw, cnt, NNr);

  const float* bIn = pw + 81920;
  const float* rbp = pw + 82048;
  const float* bO1 = pw + 82176;
  const float* Wo2p = pw + 82304;
  const float* bo2p = pw + 82560;
  const bf16* WinB = (const bf16*)(pw + BF_BASE);
  const bf16* Wo1B = (const bf16*)(pw + BF_BASE + 8192);
  const bf16* ConvB = (const bf16*)(pw + BF_BASE + 16384);  // rootB, rwB0, rwB1
  const bf16* EncU = (const bf16*)(pw + ENC_BASE);
  const bf16* EncT = (const bf16*)(pw + ENC_BASE + 8192);
  const float* bU = pw + ENC_BASE + 16384;
  const float* bT = bU + 128;

  const void* ei = d_in[4];
  const void* et = d_in[5];
  const int nb1 = (2 * NNr + 1023) / 1024;

  // ---- CSR build (bsum needs no pre-zero: scan writes all nb1 entries) ----
  count_edges<<<(NEr + 255) / 256, 256, 0, stream>>>(ei, et, flags, cnt, NEr, NNr);
  scan_blocks<<<nb1, 256, 0, stream>>>(cnt, off, bsum, 2 * NNr);
  scan_blocks<<<1, 256, 0, stream>>>(bsum, bsumsc, nullptr, nb1);
  scan_add_inv<<<(2 * NNr + 255) / 256, 256, 0, stream>>>(off, bsumsc, cnt, inv, 2 * NNr);
  fill_elist<<<(NEr + 255) / 256, 256, 0, stream>>>(ei, et, flags, off, fill, elist, NEr, NNr);

  // ---- encoders (fused with W_in) -> xb ----
  if (dDes + dNum + dCat <= 128 && dTw <= 128) {
    enc_mfma<<<(NUr + 127) / 128, 256, 0, stream>>>(d_in[0], d_in[2], d_in[3], flags, 0, 2, 3,
                                                    dDes, dNum, dCat, EncU, bU, WinB, bIn, xb,
                                                    NUr, 0);
    enc_mfma<<<(NTr + 127) / 128, 256, 0, stream>>>(d_in[1], nullptr, nullptr, flags, 1, 1, 1,
                                                    dTw, 0, 0, EncT, bT, WinB, bIn, xb, NTr,
                                                    NUr);
  } else {
    enc_gemm<<<(NUr + 63) / 64, 256, 0, stream>>>(d_in[0], d_in[6], d_in[7], flags, 0, 6, 7,
                                                  xa, NUr, dDes, 64, 0, 0);
    enc_gemm<<<(NUr + 63) / 64, 256, 0, stream>>>(d_in[2], d_in[8], d_in[9], flags, 2, 8, 9,
                                                  xa, NUr, dNum, 32, 0, 64);
    enc_gemm<<<(NUr + 63) / 64, 256, 0, stream>>>(d_in[3], d_in[10], d_in[11], flags, 3, 10,
                                                  11, xa, NUr, dCat, 32, 0, 96);
    enc_gemm<<<(NTr + 63) / 64, 256, 0, stream>>>(d_in[1], d_in[12], d_in[13], flags, 1, 12,
                                                  13, xa, NTr, dTw, 128, NUr, 0);
    mfma_lin<<<(NNr + 127) / 128, 256, 0, stream>>>(xa, WinB, bIn, xb, NNr);
  }

  const int mt32 = (NNr + 31) / 32;
  mfma_conv_f<false><<<mt32, 256, 0, stream>>>(xb, off, cnt, elist, inv, ConvB, rbp, xa,
                                               nullptr, nullptr, nullptr, nullptr, nullptr,
                                               NNr, NNr);
  mfma_conv_f<true><<<mt32, 256, 0, stream>>>(xa, off, cnt, elist, inv, ConvB, rbp, nullptr,
                                              Wo1B, bO1, Wo2p, bo2p, out, NNr, NNr);
}

extern "C" void kernel_launch(void* const* d_in, const int* in_sizes, int n_in,
                              void* d_out, int out_size, void* d_ws, size_t ws_size,
                              hipStream_t stream) {
  float* out = (float*)d_out;
  char* ws = (char*)d_ws;

  auto signal = [&](int k) {
    sig_fill<<<(out_size + 255) / 256, 256, 0, stream>>>(out, out_size, (float)(200 + k));
  };

  if (n_in != 23) { signal(1); return; }
  const int* S = in_sizes;
  if (S[7] != 64 || S[9] != 32 || S[11] != 32 || S[13] != 128) { signal(2); return; }
  if (S[15] != 128) { signal(3); return; }
  if (S[6] % 64 || S[8] % 32 || S[10] % 32 || S[12] % 128) { signal(4); return; }
  int dDes = S[6] / 64, dNum = S[8] / 32, dCat = S[10] / 32, dTw = S[12] / 128;
  if (dDes <= 0 || dTw <= 0 || S[0] % dDes || S[1] % dTw) { signal(5); return; }
  if (dDes > 101 || dNum > 101 || dCat > 101 || dTw > 101) { signal(4); return; }
  int NUr = S[0] / dDes, NTr = S[1] / dTw, NNr = NUr + NTr, NEr = S[5];
  if (S[2] != NUr * dNum || S[3] != NUr * dCat) { signal(5); return; }
  if (S[4] != 2 * NEr || NEr < 1024) { signal(6); return; }
  if (NNr >= (1 << 24)) { signal(6); return; }  // elist src-packing limit
  if (S[14] != 16384 || S[16] != 32768 || S[17] != 16384 || S[18] != 128 ||
      S[19] != 16384 || S[20] != 128 || S[21] != 256 || S[22] != 2) { signal(7); return; }
  if (out_size != NNr * 2) { signal(8); return; }

  const size_t smallBytes = (size_t)4 * ((size_t)2 * NNr * 4) + 2 * 2048 * 4 +
                            (size_t)NEr * 4 + (size_t)PW_TOTAL * 4 + 512;
  const size_t need = 2 * (size_t)NNr * 128 * 2 + smallBytes;

  if (ws_size >= need) {
    run_pipeline(d_in, S, out, ws, NUr, NTr, NEr, dDes, dNum, dCat, dTw, stream);
  } else {
    signal(9);
  }
}